// Round 3
// baseline (585.138 us; speedup 1.0000x reference)
//
#include <hip/hip_runtime.h>

// Problem constants (fixed by the reference setup)
constexpr int N_NODES = 50000;
constexpr int G = 5;
constexpr int E = 850000;            // E0 (800000) + N self-loops
constexpr int GN = G * N_NODES;      // 250000
constexpr int GE = G * E;            // 4,250,000
constexpr float SLOPE = 0.2f;

// Bucket sort parameters
constexpr int NPB = 1024;                        // nodes per bucket
constexpr int NBUK = (GN + NPB - 1) / NPB;       // 245
constexpr int EPB = 4096;                        // edges per block (256 thr x 16)
constexpr int NBLK_E = (GE + EPB - 1) / EPB;     // 1038

typedef _Float16 f16;
typedef f16 f16x4 __attribute__((ext_vector_type(4)));
typedef float f32x4 __attribute__((ext_vector_type(4)));

static __device__ __forceinline__ float lrelu(float e) {
    return e > 0.f ? e : SLOPE * e;
}
static __device__ __forceinline__ unsigned short f2h(float f) {
    union { _Float16 h; unsigned short u; } v;
    v.h = (_Float16)f;
    return v.u;
}
static __device__ __forceinline__ float h2f(unsigned short u) {
    union { unsigned short u; _Float16 h; } v;
    v.u = u;
    return (float)v.h;
}

// ---------------- pass A1: per-block bucket histogram -----------------------
__global__ __launch_bounds__(256) void k_hist(const int* __restrict__ ei,
                                              int* __restrict__ H) {
    __shared__ int hist[NBUK];
    const int t = threadIdx.x, bi = blockIdx.x;
    for (int j = t; j < NBUK; j += 256) hist[j] = 0;
    __syncthreads();
#pragma unroll
    for (int i = 0; i < 16; ++i) {
        int idx = bi * EPB + i * 256 + t;
        if (idx < GE) {
            int g = idx / E;
            int el = idx - g * E;
            int dst = ei[(size_t)g * 2 * E + E + el];
            atomicAdd(&hist[(g * N_NODES + dst) >> 10], 1);
        }
    }
    __syncthreads();
    for (int j = t; j < NBUK; j += 256) H[(size_t)bi * NBUK + j] = hist[j];
}

// ------- pass A2a: per bucket, exclusive scan of H over blocks; totals ------
__global__ __launch_bounds__(256) void k_scanH(int* __restrict__ H,
                                               int* __restrict__ T) {
    __shared__ int s[256];
    const int t = threadIdx.x, b = blockIdx.x;
    int run = 0;
    for (int c = 0; c < NBLK_E; c += 256) {
        int bi = c + t;
        int v = (bi < NBLK_E) ? H[(size_t)bi * NBUK + b] : 0;
        s[t] = v;
        for (int off = 1; off < 256; off <<= 1) {
            __syncthreads();
            int u = (t >= off) ? s[t - off] : 0;
            __syncthreads();
            s[t] += u;
        }
        __syncthreads();
        int excl = s[t] - v;
        if (bi < NBLK_E) H[(size_t)bi * NBUK + b] = run + excl;
        run += s[255];
        __syncthreads();
    }
    if (t == 0) T[b] = run;
}

// ------- pass A2b: exclusive scan of bucket totals -> bucket bases ----------
__global__ __launch_bounds__(256) void k_scanT(const int* __restrict__ T,
                                               int* __restrict__ base_g) {
    __shared__ int s[256];
    const int t = threadIdx.x;
    int v = (t < NBUK) ? T[t] : 0;
    s[t] = v;
    for (int off = 1; off < 256; off <<= 1) {
        __syncthreads();
        int u = (t >= off) ? s[t - off] : 0;
        __syncthreads();
        s[t] += u;
    }
    __syncthreads();
    if (t < NBUK) base_g[t] = s[t] - v;
    if (t == 0) base_g[NBUK] = s[255];
}

// ------- pass A3: scatter packed (dstLow10<<18 | src) into bucket groups ----
__global__ __launch_bounds__(256) void k_scatter(const int* __restrict__ ei,
                                                 const int* __restrict__ H,
                                                 const int* __restrict__ base_g,
                                                 int* __restrict__ tmp) {
    __shared__ int cnt[NBUK];
    __shared__ int off[NBUK];
    const int t = threadIdx.x, bi = blockIdx.x;
    for (int j = t; j < NBUK; j += 256) {
        cnt[j] = 0;
        off[j] = base_g[j] + H[(size_t)bi * NBUK + j];
    }
    __syncthreads();
#pragma unroll
    for (int i = 0; i < 16; ++i) {
        int idx = bi * EPB + i * 256 + t;
        if (idx < GE) {
            int g = idx / E;
            int el = idx - g * E;
            const int* eb = ei + (size_t)g * 2 * E;
            int src = eb[el];
            int dst = eb[E + el];
            int gdst = g * N_NODES + dst;
            int b = gdst >> 10;
            int rank = atomicAdd(&cnt[b], 1);
            tmp[off[b] + rank] = ((gdst & 1023) << 18) | (g * N_NODES + src);
        }
    }
}

// ------- pass B: per-bucket LDS counting sort -> rowptr/deg/csr -------------
__global__ __launch_bounds__(256) void k_build(const int* __restrict__ base_g,
                                               const int* __restrict__ tmp,
                                               int* __restrict__ rowptr,
                                               int* __restrict__ deg,
                                               int* __restrict__ csr) {
    __shared__ int degL[NPB];
    __shared__ int curL[NPB];
    __shared__ int s[256];
    const int t = threadIdx.x, b = blockIdx.x;
    const int n0 = b << 10;
    const int nn = min(NPB, GN - n0);
    const int s0 = base_g[b], s1 = base_g[b + 1];
#pragma unroll
    for (int i = 0; i < 4; ++i) degL[t * 4 + i] = 0;
    __syncthreads();
    for (int i = s0 + t; i < s1; i += 256)
        atomicAdd(&degL[tmp[i] >> 18], 1);
    __syncthreads();
    int j0 = t * 4;
    int d0 = degL[j0], d1 = degL[j0 + 1], d2 = degL[j0 + 2], d3 = degL[j0 + 3];
    int tsum = d0 + d1 + d2 + d3;
    s[t] = tsum;
    for (int off = 1; off < 256; off <<= 1) {
        __syncthreads();
        int u = (t >= off) ? s[t - off] : 0;
        __syncthreads();
        s[t] += u;
    }
    __syncthreads();
    int excl = s[t] - tsum;
    int p0 = excl, p1 = p0 + d0, p2 = p1 + d1, p3 = p2 + d2;
    curL[j0] = p0; curL[j0 + 1] = p1; curL[j0 + 2] = p2; curL[j0 + 3] = p3;
    if (j0     < nn) { rowptr[n0 + j0]     = s0 + p0; deg[n0 + j0]     = d0; }
    if (j0 + 1 < nn) { rowptr[n0 + j0 + 1] = s0 + p1; deg[n0 + j0 + 1] = d1; }
    if (j0 + 2 < nn) { rowptr[n0 + j0 + 2] = s0 + p2; deg[n0 + j0 + 2] = d2; }
    if (j0 + 3 < nn) { rowptr[n0 + j0 + 3] = s0 + p3; deg[n0 + j0 + 3] = d3; }
    __syncthreads();
    for (int i = s0 + t; i < s1; i += 256) {
        int e = tmp[i];
        int r = atomicAdd(&curL[e >> 18], 1);
        csr[s0 + r] = e & 0x3FFFF;
    }
}

// ------- prep: W1 (128x64 f32, k-major) -> W1^T hi/lo f16 [64][128] ---------
__global__ __launch_bounds__(256) void k_prepW(const float* __restrict__ W1,
                                               f16* __restrict__ WhT,
                                               f16* __restrict__ WlT) {
    int t = blockIdx.x * 256 + threadIdx.x;   // 8192 elements
    if (t >= 128 * 64) return;
    int k = t & 127;          // consecutive threads -> consecutive k (coalesced writes)
    int n = t >> 7;
    float w = W1[k * 64 + n];
    f16 h = (f16)w;
    WhT[n * 128 + k] = h;
    WlT[n * 128 + k] = (f16)(w - (float)h);
}

// --- GEMM1 via MFMA (split-fp16 for fp32 accuracy) + fused logits -----------
// Block = 4 waves, each wave 32 rows (2 M-tiles of 16). Full N=64 (4 N-tiles).
// A: x rows, loaded fp32 direct from global (16 dwordx4/lane, issued upfront),
//    split into hi/lo fp16 fragments per 16-k step.
// B: W1^T hi/lo fp16 from global (L1/L2-resident 32KB), 8B frags per step.
// acc = xh*wh + xh*wl + xl*wh (xl*wl ~ 2^-22, dropped) == fp32-accurate.
__global__ __launch_bounds__(256) void k_gemm1(const float* __restrict__ x,
                                               const f16* __restrict__ WhT,
                                               const f16* __restrict__ WlT,
                                               const float* __restrict__ a_src,
                                               const float* __restrict__ a_dst,
                                               unsigned short* __restrict__ h1f,
                                               unsigned short* __restrict__ l1,
                                               float* __restrict__ ad1) {
    const int t = threadIdx.x;
    const int lane = t & 63;
    const int wv = t >> 6;
    const int ln15 = lane & 15;
    const int q = lane >> 4;                  // quarter-wave: k-group
    const int rowBase = blockIdx.x * 128 + wv * 32;

    // ---- A loads: 2 Mtiles x 8 Ksteps x (4 consecutive fp32) ----
    const float4* x4 = (const float4*)x;
    float4 araw[2][8];
#pragma unroll
    for (int m = 0; m < 2; ++m) {
        int row = rowBase + m * 16 + ln15;
        row = row < GN ? row : GN - 1;        // clamp (pad rows compute garbage)
        const float4* xr = x4 + (size_t)row * 32 + q;
#pragma unroll
        for (int s = 0; s < 8; ++s)
            araw[m][s] = xr[s * 4];           // k = s*16 + q*4 .. +3
    }

    f32x4 acc[2][4];
#pragma unroll
    for (int m = 0; m < 2; ++m)
#pragma unroll
        for (int nt = 0; nt < 4; ++nt)
            acc[m][nt] = (f32x4){0.f, 0.f, 0.f, 0.f};

#pragma unroll
    for (int s = 0; s < 8; ++s) {
        // B fragments: lane holds W1[k = s*16 + q*4 + j][col = nt*16 + ln15]
        f16x4 bh[4], bl[4];
#pragma unroll
        for (int nt = 0; nt < 4; ++nt) {
            int col = nt * 16 + ln15;
            int o = col * 128 + s * 16 + q * 4;
            bh[nt] = *(const f16x4*)(WhT + o);
            bl[nt] = *(const f16x4*)(WlT + o);
        }
#pragma unroll
        for (int m = 0; m < 2; ++m) {
            float4 r = araw[m][s];
            f16 h0 = (f16)r.x, h1 = (f16)r.y, h2 = (f16)r.z, h3 = (f16)r.w;
            f16x4 ah = {h0, h1, h2, h3};
            f16x4 al = {(f16)(r.x - (float)h0), (f16)(r.y - (float)h1),
                        (f16)(r.z - (float)h2), (f16)(r.w - (float)h3)};
#pragma unroll
            for (int nt = 0; nt < 4; ++nt) {
                acc[m][nt] = __builtin_amdgcn_mfma_f32_16x16x16f16(ah, bh[nt], acc[m][nt], 0, 0, 0);
                acc[m][nt] = __builtin_amdgcn_mfma_f32_16x16x16f16(al, bh[nt], acc[m][nt], 0, 0, 0);
                acc[m][nt] = __builtin_amdgcn_mfma_f32_16x16x16f16(ah, bl[nt], acc[m][nt], 0, 0, 0);
            }
        }
    }

    // ---- epilogue: C[row][col], col = nt*16 + ln15, row = base + q*4 + i ----
    float aSv[4], aDv[4];
#pragma unroll
    for (int nt = 0; nt < 4; ++nt) {
        aSv[nt] = a_src[nt * 16 + ln15];
        aDv[nt] = a_dst[nt * 16 + ln15];
    }
#pragma unroll
    for (int m = 0; m < 2; ++m) {
#pragma unroll
        for (int i = 0; i < 4; ++i) {
            int row = rowBase + m * 16 + q * 4 + i;
            bool ok = row < GN;
#pragma unroll
            for (int nt = 0; nt < 4; ++nt) {
                float v = acc[m][nt][i];
                if (ok) h1f[(size_t)row * 64 + nt * 16 + ln15] = f2h(v);
                float ps = v * aSv[nt];
                float pd = v * aDv[nt];
                ps += __shfl_xor(ps, 1); ps += __shfl_xor(ps, 2); ps += __shfl_xor(ps, 4);
                pd += __shfl_xor(pd, 1); pd += __shfl_xor(pd, 2); pd += __shfl_xor(pd, 4);
                if (ok && (ln15 & 7) == 0) {
                    int head = nt * 2 + (ln15 >> 3);
                    l1[(size_t)row * 8 + head] = f2h(ps);
                    ad1[row * 8 + head] = pd;
                }
            }
        }
    }
}

// ------- layer-1 gather: 2 dsts per wave; per 32-lane half: 4 edge-slots x 8 heads
__global__ __launch_bounds__(256) void k_layer1(const int* __restrict__ rowptr,
                                                const int* __restrict__ deg,
                                                const int* __restrict__ csr,
                                                const unsigned short* __restrict__ h1f,
                                                const unsigned short* __restrict__ l1,
                                                const float* __restrict__ ad1,
                                                unsigned short* __restrict__ out1h) {
    const int tt = threadIdx.x & 63;
    const int h  = tt & 7;            // head (8 channels each)
    const int es = (tt >> 3) & 3;     // edge slot within dst
    const int d  = blockIdx.x * 8 + (threadIdx.x >> 5);   // dst node (2 per wave)

    const int start = rowptr[d];
    const int dg    = deg[d];
    const float ad  = ad1[d * 8 + h];

    const unsigned int* h1d = (const unsigned int*)h1f;   // row = 32 dwords
    float a0 = 0.f, a1 = 0.f, a2 = 0.f, a3 = 0.f;
    float a4 = 0.f, a5 = 0.f, a6 = 0.f, a7 = 0.f;
    float den = 0.f;

    for (int j = es; j < dg; j += 4) {
        int s = csr[start + j];
        float w = __expf(lrelu(h2f(l1[(size_t)s * 8 + h]) + ad));
        den += w;
        const uint4 gp = *(const uint4*)(h1d + (size_t)s * 32 + h * 4);  // 16B
        a0 += w * h2f((unsigned short)(gp.x & 0xffff));
        a1 += w * h2f((unsigned short)(gp.x >> 16));
        a2 += w * h2f((unsigned short)(gp.y & 0xffff));
        a3 += w * h2f((unsigned short)(gp.y >> 16));
        a4 += w * h2f((unsigned short)(gp.z & 0xffff));
        a5 += w * h2f((unsigned short)(gp.z >> 16));
        a6 += w * h2f((unsigned short)(gp.w & 0xffff));
        a7 += w * h2f((unsigned short)(gp.w >> 16));
    }
    a0 += __shfl_xor(a0, 8);  a0 += __shfl_xor(a0, 16);
    a1 += __shfl_xor(a1, 8);  a1 += __shfl_xor(a1, 16);
    a2 += __shfl_xor(a2, 8);  a2 += __shfl_xor(a2, 16);
    a3 += __shfl_xor(a3, 8);  a3 += __shfl_xor(a3, 16);
    a4 += __shfl_xor(a4, 8);  a4 += __shfl_xor(a4, 16);
    a5 += __shfl_xor(a5, 8);  a5 += __shfl_xor(a5, 16);
    a6 += __shfl_xor(a6, 8);  a6 += __shfl_xor(a6, 16);
    a7 += __shfl_xor(a7, 8);  a7 += __shfl_xor(a7, 16);
    den += __shfl_xor(den, 8); den += __shfl_xor(den, 16);

    if (es == 0) {
        float inv = 1.f / (den + 1e-16f);
        unsigned int p0 = (unsigned int)f2h(a0 * inv) | ((unsigned int)f2h(a1 * inv) << 16);
        unsigned int p1 = (unsigned int)f2h(a2 * inv) | ((unsigned int)f2h(a3 * inv) << 16);
        unsigned int p2 = (unsigned int)f2h(a4 * inv) | ((unsigned int)f2h(a5 * inv) << 16);
        unsigned int p3 = (unsigned int)f2h(a6 * inv) | ((unsigned int)f2h(a7 * inv) << 16);
        *(uint4*)(out1h + (size_t)d * 64 + h * 8) = make_uint4(p0, p1, p2, p3);
    }
}

// --- GEMM2 + fused logits: h2r[GN][20] fp16 (16 ch + logit in one 40B row) --
__global__ __launch_bounds__(256) void k_gemm2(const unsigned short* __restrict__ agg1,
                                               const float* __restrict__ b1,
                                               const float* __restrict__ W2,
                                               const float* __restrict__ a_src,
                                               const float* __restrict__ a_dst,
                                               unsigned short* __restrict__ h2r,
                                               float* __restrict__ ad2) {
    __shared__ float As[64][65];
    __shared__ float Bs[64][20];
    __shared__ float aS[16], aD[16];
    const int t = threadIdx.x;
    const int rowBase = blockIdx.x * 64;

    {
        int k = t >> 2, c = (t & 3) << 2;
        float4 w = ((const float4*)W2)[t];
        Bs[k][c] = w.x; Bs[k][c + 1] = w.y; Bs[k][c + 2] = w.z; Bs[k][c + 3] = w.w;
    }
    if (t < 16) { aS[t] = a_src[t]; aD[t] = a_dst[t]; }
    const ushort4* a4p = (const ushort4*)agg1;
    const float4* b14 = (const float4*)b1;
#pragma unroll
    for (int i = 0; i < 4; ++i) {
        int v = t + i * 256;
        int r = v >> 4;
        int kq = v & 15;
        int row = rowBase + r;
        float ax = 0.f, ay = 0.f, az = 0.f, aw = 0.f;
        if (row < GN) {
            ushort4 a = a4p[row * 16 + kq];
            float4 bb = b14[kq];
            ax = fmaxf(h2f(a.x) + bb.x, 0.f);
            ay = fmaxf(h2f(a.y) + bb.y, 0.f);
            az = fmaxf(h2f(a.z) + bb.z, 0.f);
            aw = fmaxf(h2f(a.w) + bb.w, 0.f);
        }
        int kk = kq << 2;
        As[kk][r] = ax; As[kk + 1][r] = ay; As[kk + 2][r] = az; As[kk + 3][r] = aw;
    }
    __syncthreads();
    const int r = t >> 2;
    const int cg = (t & 3) << 2;
    float acc0 = 0.f, acc1 = 0.f, acc2 = 0.f, acc3 = 0.f;
#pragma unroll 8
    for (int k = 0; k < 64; ++k) {
        float a = As[k][r];
        float4 b = *(const float4*)&Bs[k][cg];
        acc0 += a * b.x; acc1 += a * b.y; acc2 += a * b.z; acc3 += a * b.w;
    }
    float as_p = acc0 * aS[cg] + acc1 * aS[cg + 1] + acc2 * aS[cg + 2] + acc3 * aS[cg + 3];
    float ad_p = acc0 * aD[cg] + acc1 * aD[cg + 1] + acc2 * aD[cg + 2] + acc3 * aD[cg + 3];
    as_p += __shfl_xor(as_p, 1); as_p += __shfl_xor(as_p, 2);
    ad_p += __shfl_xor(ad_p, 1); ad_p += __shfl_xor(ad_p, 2);
    int row = rowBase + r;
    if (row < GN) {
        ushort4 fv = make_ushort4(f2h(acc0), f2h(acc1), f2h(acc2), f2h(acc3));
        *(ushort4*)(h2r + (size_t)row * 20 + cg) = fv;   // row*40B + cg*2 is 8B-aligned
        if ((t & 3) == 0) {
            h2r[(size_t)row * 20 + 16] = f2h(as_p);
            ad2[row] = ad_p;
        }
    }
}

// ------- layer-2 gather: one wave/dst, 8 edge-slots x 8 ch-pairs ------------
__global__ __launch_bounds__(256) void k_layer2(const int* __restrict__ rowptr,
                                                const int* __restrict__ deg,
                                                const int* __restrict__ csr,
                                                const unsigned short* __restrict__ h2r,
                                                const float* __restrict__ ad2,
                                                float* __restrict__ out2) {
    int d = __builtin_amdgcn_readfirstlane(blockIdx.x * 4 + (threadIdx.x >> 6));
    int tt = threadIdx.x & 63;
    int p = tt & 7;                   // channel pair (ch 2p, 2p+1)
    int sub = tt >> 3;                // 8 edge slots
    int start = rowptr[d];
    int dg = deg[d];
    float ad = ad2[d];
    int sv = csr[start + min(tt, dg - 1)];   // whole adjacency in registers
    int full = min(dg, 64);
    float den = 0.f, accx = 0.f, accy = 0.f;
    for (int base = 0; base < full; base += 8) {
        int j = base + sub;
        bool val = j < full;
        int s = __shfl(sv, j < 64 ? j : 0);
        const unsigned short* r = h2r + (size_t)s * 20;
        float w = val ? __expf(lrelu(h2f(r[16]) + ad)) : 0.f;
        unsigned int gp = *(const unsigned int*)(r + p * 2);
        den += w;
        accx += w * h2f((unsigned short)(gp & 0xffff));
        accy += w * h2f((unsigned short)(gp >> 16));
    }
    // tail for deg > 64 (essentially never)
    for (int base = 64; base < dg; base += 8) {
        int j = base + sub;
        bool val = j < dg;
        int s = csr[start + (val ? j : 0)];
        const unsigned short* r = h2r + (size_t)s * 20;
        float w = val ? __expf(lrelu(h2f(r[16]) + ad)) : 0.f;
        unsigned int gp = *(const unsigned int*)(r + p * 2);
        den += w;
        accx += w * h2f((unsigned short)(gp & 0xffff));
        accy += w * h2f((unsigned short)(gp >> 16));
    }
    accx += __shfl_xor(accx, 8); accx += __shfl_xor(accx, 16); accx += __shfl_xor(accx, 32);
    accy += __shfl_xor(accy, 8); accy += __shfl_xor(accy, 16); accy += __shfl_xor(accy, 32);
    den  += __shfl_xor(den, 8);  den  += __shfl_xor(den, 16);  den  += __shfl_xor(den, 32);
    if (sub == 0) {
        float inv = 1.f / (den + 1e-16f);
        ((float2*)out2)[(size_t)d * 8 + p] = make_float2(accx * inv, accy * inv);
    }
}

// -------- final: out[n,2] = concat_g(out2[g,n,:]+b2) @ Wf + bf --------------
__global__ __launch_bounds__(256) void k_final(const float* __restrict__ agg2,
                                               const float* __restrict__ b2,
                                               const float* __restrict__ Wf,
                                               const float* __restrict__ bf,
                                               float* __restrict__ out) {
    int n = blockIdx.x * 256 + threadIdx.x;
    if (n >= N_NODES) return;
    float o0 = bf[0], o1 = bf[1];
#pragma unroll
    for (int g = 0; g < G; ++g) {
        const float4* v4 = (const float4*)agg2 + (size_t)(g * N_NODES + n) * 4;
#pragma unroll
        for (int q = 0; q < 4; ++q) {
            float4 v = v4[q];
            float4 b = ((const float4*)b2)[q];
            v.x += b.x; v.y += b.y; v.z += b.z; v.w += b.w;
            int kb = g * 16 + q * 4;
            o0 += v.x * Wf[(kb + 0) * 2]     + v.y * Wf[(kb + 1) * 2]
                + v.z * Wf[(kb + 2) * 2]     + v.w * Wf[(kb + 3) * 2];
            o1 += v.x * Wf[(kb + 0) * 2 + 1] + v.y * Wf[(kb + 1) * 2 + 1]
                + v.z * Wf[(kb + 2) * 2 + 1] + v.w * Wf[(kb + 3) * 2 + 1];
        }
    }
    out[n * 2]     = o0;
    out[n * 2 + 1] = o1;
}

extern "C" void kernel_launch(void* const* d_in, const int* in_sizes, int n_in,
                              void* d_out, int out_size, void* d_ws, size_t ws_size,
                              hipStream_t stream) {
    const float* x      = (const float*)d_in[0];
    const int*   ei     = (const int*)d_in[1];
    const float* W1     = (const float*)d_in[2];
    const float* a_src1 = (const float*)d_in[3];
    const float* a_dst1 = (const float*)d_in[4];
    const float* b1     = (const float*)d_in[5];
    const float* W2     = (const float*)d_in[6];
    const float* a_src2 = (const float*)d_in[7];
    const float* a_dst2 = (const float*)d_in[8];
    const float* b2     = (const float*)d_in[9];
    const float* Wf     = (const float*)d_in[10];
    const float* bf     = (const float*)d_in[11];
    float* out = (float*)d_out;

    // workspace layout (lifetime aliasing):
    //   region A (36 MB): h1f[GN*64 u16] + l1[GN*8 u16]   (gemm1 -> layer1)
    //                     -> h2r[GN*20 u16] + out2[GN*16 f32]
    //   region B (32 MB): out1h[GN*64 u16]                (layer1 -> gemm2)
    //   region C (8 MB):  ad1[GN*8 f32] -> ad2[GN f32]
    //   ints: rowptr, deg, base_g, T, H, tmp, csr
    //   tail: W1^T hi/lo fp16 (32 KB)
    unsigned short* h1f = (unsigned short*)d_ws;             // GN*64 u16 (128B rows)
    unsigned short* l1  = h1f + (size_t)GN * 64;             // GN*8 u16
    unsigned short* h2r = h1f;                               // GN*20 u16 (alias)
    float* out2 = (float*)(h2r + (size_t)GN * 20);           // GN*16 f32 (alias; 8B-aligned)
    unsigned short* out1h = h1f + (size_t)GN * 72;           // GN*64 u16
    float* ad1  = (float*)(out1h + (size_t)GN * 64);         // GN*8 f32
    float* ad2  = ad1;                                       // GN (alias)
    int*   iws    = (int*)(ad1 + (size_t)GN * 8);
    int*   rowptr = iws;                                     // GN
    int*   deg    = rowptr + GN;                             // GN
    int*   base_g = deg + GN;                                // NBUK+1
    int*   T      = base_g + (NBUK + 1);                     // NBUK
    int*   H      = T + NBUK;                                // NBLK_E*NBUK
    int*   tmp    = H + (size_t)NBLK_E * NBUK;               // GE
    int*   csr    = tmp + GE;                                // GE
    uintptr_t wp = ((uintptr_t)(csr + GE) + 15) & ~(uintptr_t)15;
    f16* WhT = (f16*)wp;                                     // 64*128 f16
    f16* WlT = WhT + 64 * 128;                               // 64*128 f16

    // CSR build via bucket sort (no global atomics, coalesced writes)
    k_hist   <<<NBLK_E, 256, 0, stream>>>(ei, H);
    k_scanH  <<<NBUK,   256, 0, stream>>>(H, T);
    k_scanT  <<<1,      256, 0, stream>>>(T, base_g);
    k_scatter<<<NBLK_E, 256, 0, stream>>>(ei, H, base_g, tmp);
    k_build  <<<NBUK,   256, 0, stream>>>(base_g, tmp, rowptr, deg, csr);

    k_prepW  <<<32, 256, 0, stream>>>(W1, WhT, WlT);
    k_gemm1  <<<(GN + 127) / 128, 256, 0, stream>>>(x, WhT, WlT, a_src1, a_dst1, h1f, l1, ad1);
    k_layer1 <<<GN / 8, 256, 0, stream>>>(rowptr, deg, csr, h1f, l1, ad1, out1h);
    k_gemm2  <<<(GN + 63) / 64, 256, 0, stream>>>(out1h, b1, W2, a_src2, a_dst2, h2r, ad2);
    k_layer2 <<<GN / 4, 256, 0, stream>>>(rowptr, deg, csr, h2r, ad2, out2);
    k_final  <<<(N_NODES + 255) / 256, 256, 0, stream>>>(out2, b2, Wf, bf, out);
}

// Round 4
// 537.333 us; speedup vs baseline: 1.0890x; 1.0890x over previous
//
#include <hip/hip_runtime.h>

// Problem constants (fixed by the reference setup)
constexpr int N_NODES = 50000;
constexpr int G = 5;
constexpr int E = 850000;            // E0 (800000) + N self-loops
constexpr int GN = G * N_NODES;      // 250000
constexpr int GE = G * E;            // 4,250,000
constexpr float SLOPE = 0.2f;

// Bucket sort parameters
constexpr int NPB = 1024;                        // nodes per bucket
constexpr int NBUK = (GN + NPB - 1) / NPB;       // 245
constexpr int EPB = 4096;                        // edges per block (256 thr x 16)
constexpr int NBLK_E = (GE + EPB - 1) / EPB;     // 1038

typedef _Float16 f16;
typedef f16 f16x4 __attribute__((ext_vector_type(4)));
typedef float f32x4 __attribute__((ext_vector_type(4)));

static __device__ __forceinline__ float lrelu(float e) {
    return e > 0.f ? e : SLOPE * e;
}
static __device__ __forceinline__ unsigned short f2h(float f) {
    union { _Float16 h; unsigned short u; } v;
    v.h = (_Float16)f;
    return v.u;
}
static __device__ __forceinline__ float h2f(unsigned short u) {
    union { unsigned short u; _Float16 h; } v;
    v.u = u;
    return (float)v.h;
}
static __device__ __forceinline__ f16x4 u2h4(uint2 u) {
    union { uint2 u; f16x4 h; } c;
    c.u = u;
    return c.h;
}

// ---------------- pass A1: per-block bucket histogram -----------------------
__global__ __launch_bounds__(256) void k_hist(const int* __restrict__ ei,
                                              int* __restrict__ H) {
    __shared__ int hist[NBUK];
    const int t = threadIdx.x, bi = blockIdx.x;
    for (int j = t; j < NBUK; j += 256) hist[j] = 0;
    __syncthreads();
#pragma unroll
    for (int i = 0; i < 16; ++i) {
        int idx = bi * EPB + i * 256 + t;
        if (idx < GE) {
            int g = idx / E;
            int el = idx - g * E;
            int dst = ei[(size_t)g * 2 * E + E + el];
            atomicAdd(&hist[(g * N_NODES + dst) >> 10], 1);
        }
    }
    __syncthreads();
    for (int j = t; j < NBUK; j += 256) H[(size_t)bi * NBUK + j] = hist[j];
}

// ------- pass A2a: per bucket, exclusive scan of H over blocks; totals ------
__global__ __launch_bounds__(256) void k_scanH(int* __restrict__ H,
                                               int* __restrict__ T) {
    __shared__ int s[256];
    const int t = threadIdx.x, b = blockIdx.x;
    int run = 0;
    for (int c = 0; c < NBLK_E; c += 256) {
        int bi = c + t;
        int v = (bi < NBLK_E) ? H[(size_t)bi * NBUK + b] : 0;
        s[t] = v;
        for (int off = 1; off < 256; off <<= 1) {
            __syncthreads();
            int u = (t >= off) ? s[t - off] : 0;
            __syncthreads();
            s[t] += u;
        }
        __syncthreads();
        int excl = s[t] - v;
        if (bi < NBLK_E) H[(size_t)bi * NBUK + b] = run + excl;
        run += s[255];
        __syncthreads();
    }
    if (t == 0) T[b] = run;
}

// ------- pass A2b: exclusive scan of bucket totals -> bucket bases ----------
__global__ __launch_bounds__(256) void k_scanT(const int* __restrict__ T,
                                               int* __restrict__ base_g) {
    __shared__ int s[256];
    const int t = threadIdx.x;
    int v = (t < NBUK) ? T[t] : 0;
    s[t] = v;
    for (int off = 1; off < 256; off <<= 1) {
        __syncthreads();
        int u = (t >= off) ? s[t - off] : 0;
        __syncthreads();
        s[t] += u;
    }
    __syncthreads();
    if (t < NBUK) base_g[t] = s[t] - v;
    if (t == 0) base_g[NBUK] = s[255];
}

// ------- pass A3: scatter packed (dstLow10<<18 | src) into bucket groups ----
__global__ __launch_bounds__(256) void k_scatter(const int* __restrict__ ei,
                                                 const int* __restrict__ H,
                                                 const int* __restrict__ base_g,
                                                 int* __restrict__ tmp) {
    __shared__ int cnt[NBUK];
    __shared__ int off[NBUK];
    const int t = threadIdx.x, bi = blockIdx.x;
    for (int j = t; j < NBUK; j += 256) {
        cnt[j] = 0;
        off[j] = base_g[j] + H[(size_t)bi * NBUK + j];
    }
    __syncthreads();
#pragma unroll
    for (int i = 0; i < 16; ++i) {
        int idx = bi * EPB + i * 256 + t;
        if (idx < GE) {
            int g = idx / E;
            int el = idx - g * E;
            const int* eb = ei + (size_t)g * 2 * E;
            int src = eb[el];
            int dst = eb[E + el];
            int gdst = g * N_NODES + dst;
            int b = gdst >> 10;
            int rank = atomicAdd(&cnt[b], 1);
            tmp[off[b] + rank] = ((gdst & 1023) << 18) | (g * N_NODES + src);
        }
    }
}

// ------- pass B: per-bucket LDS counting sort -> rowptr/deg/csr -------------
__global__ __launch_bounds__(256) void k_build(const int* __restrict__ base_g,
                                               const int* __restrict__ tmp,
                                               int* __restrict__ rowptr,
                                               int* __restrict__ deg,
                                               int* __restrict__ csr) {
    __shared__ int degL[NPB];
    __shared__ int curL[NPB];
    __shared__ int s[256];
    const int t = threadIdx.x, b = blockIdx.x;
    const int n0 = b << 10;
    const int nn = min(NPB, GN - n0);
    const int s0 = base_g[b], s1 = base_g[b + 1];
#pragma unroll
    for (int i = 0; i < 4; ++i) degL[t * 4 + i] = 0;
    __syncthreads();
    for (int i = s0 + t; i < s1; i += 256)
        atomicAdd(&degL[tmp[i] >> 18], 1);
    __syncthreads();
    int j0 = t * 4;
    int d0 = degL[j0], d1 = degL[j0 + 1], d2 = degL[j0 + 2], d3 = degL[j0 + 3];
    int tsum = d0 + d1 + d2 + d3;
    s[t] = tsum;
    for (int off = 1; off < 256; off <<= 1) {
        __syncthreads();
        int u = (t >= off) ? s[t - off] : 0;
        __syncthreads();
        s[t] += u;
    }
    __syncthreads();
    int excl = s[t] - tsum;
    int p0 = excl, p1 = p0 + d0, p2 = p1 + d1, p3 = p2 + d2;
    curL[j0] = p0; curL[j0 + 1] = p1; curL[j0 + 2] = p2; curL[j0 + 3] = p3;
    if (j0     < nn) { rowptr[n0 + j0]     = s0 + p0; deg[n0 + j0]     = d0; }
    if (j0 + 1 < nn) { rowptr[n0 + j0 + 1] = s0 + p1; deg[n0 + j0 + 1] = d1; }
    if (j0 + 2 < nn) { rowptr[n0 + j0 + 2] = s0 + p2; deg[n0 + j0 + 2] = d2; }
    if (j0 + 3 < nn) { rowptr[n0 + j0 + 3] = s0 + p3; deg[n0 + j0 + 3] = d3; }
    __syncthreads();
    for (int i = s0 + t; i < s1; i += 256) {
        int e = tmp[i];
        int r = atomicAdd(&curL[e >> 18], 1);
        csr[s0 + r] = e & 0x3FFFF;
    }
}

// ------- prep: W1 (128x64 f32, k-major) -> W1^T hi/lo f16 [64][128] ---------
__global__ __launch_bounds__(256) void k_prepW(const float* __restrict__ W1,
                                               f16* __restrict__ WhT,
                                               f16* __restrict__ WlT) {
    int t = blockIdx.x * 256 + threadIdx.x;   // 8192 elements
    if (t >= 128 * 64) return;
    int k = t & 127;          // consecutive threads -> consecutive k (coalesced writes)
    int n = t >> 7;
    float w = W1[k * 64 + n];
    f16 h = (f16)w;
    WhT[n * 128 + k] = h;
    WlT[n * 128 + k] = (f16)(w - (float)h);
}

// --- GEMM1 via MFMA (split-fp16 for fp32 accuracy) + fused logits -----------
// Block = 4 waves x 32 rows. A: 16 dwordx4/lane issued upfront, HELD in regs
// (launch_bounds(256,3) -> ~168 VGPR budget). B: W1^T hi/lo staged once into
// LDS as q-XOR-swizzled uint4 slots {bh8B, bl8B}; K-loop reads 4 ds_read_b128
// per step (conflict-free), zero global loads in the loop.
// acc = xh*wh + xl*wh + xh*wl (xl*wl ~ 2^-22, dropped) == fp32-accurate.
__global__ __launch_bounds__(256, 3) void k_gemm1(const float* __restrict__ x,
                                               const f16* __restrict__ WhT,
                                               const f16* __restrict__ WlT,
                                               const float* __restrict__ a_src,
                                               const float* __restrict__ a_dst,
                                               unsigned short* __restrict__ h1f,
                                               unsigned short* __restrict__ l1,
                                               float* __restrict__ ad1) {
    __shared__ uint4 Bls[2048];               // 32 KB: slot kc*64 + (col^(kc&3))
    const int t = threadIdx.x;
    const int lane = t & 63;
    const int wv = t >> 6;
    const int ln15 = lane & 15;
    const int q = lane >> 4;                  // quarter-wave: k-group
    const int rowBase = blockIdx.x * 128 + wv * 32;

    // ---- A loads: 2 Mtiles x 8 Ksteps x (4 consecutive fp32), held in regs ----
    const float4* x4 = (const float4*)x;
    float4 araw[2][8];
#pragma unroll
    for (int m = 0; m < 2; ++m) {
        int row = rowBase + m * 16 + ln15;
        row = row < GN ? row : GN - 1;        // clamp (pad rows compute garbage)
        const float4* xr = x4 + (size_t)row * 32 + q;
#pragma unroll
        for (int s = 0; s < 8; ++s)
            araw[m][s] = xr[s * 4];           // k = s*16 + q*4 .. +3
    }

    // ---- stage B into LDS (coalesced linear reads, swizzled writes) ----
    const uint2* WhT2 = (const uint2*)WhT;    // v-th 8B chunk = W col v>>5, k (v&31)*4
    const uint2* WlT2 = (const uint2*)WlT;
#pragma unroll
    for (int i = 0; i < 8; ++i) {
        int v = t + i * 256;                  // 0..2047
        int col = v >> 5, kc = v & 31;
        uint2 bh = WhT2[v];
        uint2 bl = WlT2[v];
        Bls[kc * 64 + (col ^ (kc & 3))] = make_uint4(bh.x, bh.y, bl.x, bl.y);
    }
    __syncthreads();

    f32x4 acc[2][4];
#pragma unroll
    for (int m = 0; m < 2; ++m)
#pragma unroll
        for (int nt = 0; nt < 4; ++nt)
            acc[m][nt] = (f32x4){0.f, 0.f, 0.f, 0.f};

#pragma unroll
    for (int s = 0; s < 8; ++s) {
        // B fragments: lane holds W1[k = s*16 + q*4 + j][col = nt*16 + ln15]
        f16x4 bh[4], bl[4];
#pragma unroll
        for (int nt = 0; nt < 4; ++nt) {
            uint4 b = Bls[(s * 4 + q) * 64 + ((nt * 16 + ln15) ^ q)];
            bh[nt] = u2h4(make_uint2(b.x, b.y));
            bl[nt] = u2h4(make_uint2(b.z, b.w));
        }
#pragma unroll
        for (int m = 0; m < 2; ++m) {
            float4 r = araw[m][s];
            f16 h0 = (f16)r.x, h1 = (f16)r.y, h2 = (f16)r.z, h3 = (f16)r.w;
            f16x4 ah = {h0, h1, h2, h3};
            f16x4 al = {(f16)(r.x - (float)h0), (f16)(r.y - (float)h1),
                        (f16)(r.z - (float)h2), (f16)(r.w - (float)h3)};
#pragma unroll
            for (int nt = 0; nt < 4; ++nt) {
                acc[m][nt] = __builtin_amdgcn_mfma_f32_16x16x16f16(ah, bh[nt], acc[m][nt], 0, 0, 0);
                acc[m][nt] = __builtin_amdgcn_mfma_f32_16x16x16f16(al, bh[nt], acc[m][nt], 0, 0, 0);
                acc[m][nt] = __builtin_amdgcn_mfma_f32_16x16x16f16(ah, bl[nt], acc[m][nt], 0, 0, 0);
            }
        }
    }

    // ---- epilogue: C[row][col], col = nt*16 + ln15, row = base + q*4 + i ----
    float aSv[4], aDv[4];
#pragma unroll
    for (int nt = 0; nt < 4; ++nt) {
        aSv[nt] = a_src[nt * 16 + ln15];
        aDv[nt] = a_dst[nt * 16 + ln15];
    }
#pragma unroll
    for (int m = 0; m < 2; ++m) {
#pragma unroll
        for (int i = 0; i < 4; ++i) {
            int row = rowBase + m * 16 + q * 4 + i;
            bool ok = row < GN;
#pragma unroll
            for (int nt = 0; nt < 4; ++nt) {
                float v = acc[m][nt][i];
                if (ok) h1f[(size_t)row * 64 + nt * 16 + ln15] = f2h(v);
                float ps = v * aSv[nt];
                float pd = v * aDv[nt];
                ps += __shfl_xor(ps, 1); ps += __shfl_xor(ps, 2); ps += __shfl_xor(ps, 4);
                pd += __shfl_xor(pd, 1); pd += __shfl_xor(pd, 2); pd += __shfl_xor(pd, 4);
                if (ok && (ln15 & 7) == 0) {
                    int head = nt * 2 + (ln15 >> 3);
                    l1[(size_t)row * 8 + head] = f2h(ps);
                    ad1[row * 8 + head] = pd;
                }
            }
        }
    }
}

// ------- layer-1 gather: 2 dsts per wave; per 32-lane half: 4 edge-slots x 8 heads
__global__ __launch_bounds__(256) void k_layer1(const int* __restrict__ rowptr,
                                                const int* __restrict__ deg,
                                                const int* __restrict__ csr,
                                                const unsigned short* __restrict__ h1f,
                                                const unsigned short* __restrict__ l1,
                                                const float* __restrict__ ad1,
                                                unsigned short* __restrict__ out1h) {
    const int tt = threadIdx.x & 63;
    const int h  = tt & 7;            // head (8 channels each)
    const int es = (tt >> 3) & 3;     // edge slot within dst
    const int d  = blockIdx.x * 8 + (threadIdx.x >> 5);   // dst node (2 per wave)

    const int start = rowptr[d];
    const int dg    = deg[d];
    const float ad  = ad1[d * 8 + h];

    const unsigned int* h1d = (const unsigned int*)h1f;   // row = 32 dwords
    float a0 = 0.f, a1 = 0.f, a2 = 0.f, a3 = 0.f;
    float a4 = 0.f, a5 = 0.f, a6 = 0.f, a7 = 0.f;
    float den = 0.f;

    for (int j = es; j < dg; j += 4) {
        int s = csr[start + j];
        float w = __expf(lrelu(h2f(l1[(size_t)s * 8 + h]) + ad));
        den += w;
        const uint4 gp = *(const uint4*)(h1d + (size_t)s * 32 + h * 4);  // 16B
        a0 += w * h2f((unsigned short)(gp.x & 0xffff));
        a1 += w * h2f((unsigned short)(gp.x >> 16));
        a2 += w * h2f((unsigned short)(gp.y & 0xffff));
        a3 += w * h2f((unsigned short)(gp.y >> 16));
        a4 += w * h2f((unsigned short)(gp.z & 0xffff));
        a5 += w * h2f((unsigned short)(gp.z >> 16));
        a6 += w * h2f((unsigned short)(gp.w & 0xffff));
        a7 += w * h2f((unsigned short)(gp.w >> 16));
    }
    a0 += __shfl_xor(a0, 8);  a0 += __shfl_xor(a0, 16);
    a1 += __shfl_xor(a1, 8);  a1 += __shfl_xor(a1, 16);
    a2 += __shfl_xor(a2, 8);  a2 += __shfl_xor(a2, 16);
    a3 += __shfl_xor(a3, 8);  a3 += __shfl_xor(a3, 16);
    a4 += __shfl_xor(a4, 8);  a4 += __shfl_xor(a4, 16);
    a5 += __shfl_xor(a5, 8);  a5 += __shfl_xor(a5, 16);
    a6 += __shfl_xor(a6, 8);  a6 += __shfl_xor(a6, 16);
    a7 += __shfl_xor(a7, 8);  a7 += __shfl_xor(a7, 16);
    den += __shfl_xor(den, 8); den += __shfl_xor(den, 16);

    if (es == 0) {
        float inv = 1.f / (den + 1e-16f);
        unsigned int p0 = (unsigned int)f2h(a0 * inv) | ((unsigned int)f2h(a1 * inv) << 16);
        unsigned int p1 = (unsigned int)f2h(a2 * inv) | ((unsigned int)f2h(a3 * inv) << 16);
        unsigned int p2 = (unsigned int)f2h(a4 * inv) | ((unsigned int)f2h(a5 * inv) << 16);
        unsigned int p3 = (unsigned int)f2h(a6 * inv) | ((unsigned int)f2h(a7 * inv) << 16);
        *(uint4*)(out1h + (size_t)d * 64 + h * 8) = make_uint4(p0, p1, p2, p3);
    }
}

// --- GEMM2 + fused logits: h2r[GN][20] fp16 (16 ch + logit in one 40B row) --
__global__ __launch_bounds__(256) void k_gemm2(const unsigned short* __restrict__ agg1,
                                               const float* __restrict__ b1,
                                               const float* __restrict__ W2,
                                               const float* __restrict__ a_src,
                                               const float* __restrict__ a_dst,
                                               unsigned short* __restrict__ h2r,
                                               float* __restrict__ ad2) {
    __shared__ float As[64][65];
    __shared__ float Bs[64][20];
    __shared__ float aS[16], aD[16];
    const int t = threadIdx.x;
    const int rowBase = blockIdx.x * 64;

    {
        int k = t >> 2, c = (t & 3) << 2;
        float4 w = ((const float4*)W2)[t];
        Bs[k][c] = w.x; Bs[k][c + 1] = w.y; Bs[k][c + 2] = w.z; Bs[k][c + 3] = w.w;
    }
    if (t < 16) { aS[t] = a_src[t]; aD[t] = a_dst[t]; }
    const ushort4* a4p = (const ushort4*)agg1;
    const float4* b14 = (const float4*)b1;
#pragma unroll
    for (int i = 0; i < 4; ++i) {
        int v = t + i * 256;
        int r = v >> 4;
        int kq = v & 15;
        int row = rowBase + r;
        float ax = 0.f, ay = 0.f, az = 0.f, aw = 0.f;
        if (row < GN) {
            ushort4 a = a4p[row * 16 + kq];
            float4 bb = b14[kq];
            ax = fmaxf(h2f(a.x) + bb.x, 0.f);
            ay = fmaxf(h2f(a.y) + bb.y, 0.f);
            az = fmaxf(h2f(a.z) + bb.z, 0.f);
            aw = fmaxf(h2f(a.w) + bb.w, 0.f);
        }
        int kk = kq << 2;
        As[kk][r] = ax; As[kk + 1][r] = ay; As[kk + 2][r] = az; As[kk + 3][r] = aw;
    }
    __syncthreads();
    const int r = t >> 2;
    const int cg = (t & 3) << 2;
    float acc0 = 0.f, acc1 = 0.f, acc2 = 0.f, acc3 = 0.f;
#pragma unroll 8
    for (int k = 0; k < 64; ++k) {
        float a = As[k][r];
        float4 b = *(const float4*)&Bs[k][cg];
        acc0 += a * b.x; acc1 += a * b.y; acc2 += a * b.z; acc3 += a * b.w;
    }
    float as_p = acc0 * aS[cg] + acc1 * aS[cg + 1] + acc2 * aS[cg + 2] + acc3 * aS[cg + 3];
    float ad_p = acc0 * aD[cg] + acc1 * aD[cg + 1] + acc2 * aD[cg + 2] + acc3 * aD[cg + 3];
    as_p += __shfl_xor(as_p, 1); as_p += __shfl_xor(as_p, 2);
    ad_p += __shfl_xor(ad_p, 1); ad_p += __shfl_xor(ad_p, 2);
    int row = rowBase + r;
    if (row < GN) {
        ushort4 fv = make_ushort4(f2h(acc0), f2h(acc1), f2h(acc2), f2h(acc3));
        *(ushort4*)(h2r + (size_t)row * 20 + cg) = fv;   // row*40B + cg*2 is 8B-aligned
        if ((t & 3) == 0) {
            h2r[(size_t)row * 20 + 16] = f2h(as_p);
            ad2[row] = ad_p;
        }
    }
}

// ------- layer-2 gather: one wave/dst, 8 edge-slots x 8 ch-pairs ------------
__global__ __launch_bounds__(256) void k_layer2(const int* __restrict__ rowptr,
                                                const int* __restrict__ deg,
                                                const int* __restrict__ csr,
                                                const unsigned short* __restrict__ h2r,
                                                const float* __restrict__ ad2,
                                                float* __restrict__ out2) {
    int d = __builtin_amdgcn_readfirstlane(blockIdx.x * 4 + (threadIdx.x >> 6));
    int tt = threadIdx.x & 63;
    int p = tt & 7;                   // channel pair (ch 2p, 2p+1)
    int sub = tt >> 3;                // 8 edge slots
    int start = rowptr[d];
    int dg = deg[d];
    float ad = ad2[d];
    int sv = csr[start + min(tt, dg - 1)];   // whole adjacency in registers
    int full = min(dg, 64);
    float den = 0.f, accx = 0.f, accy = 0.f;
    for (int base = 0; base < full; base += 8) {
        int j = base + sub;
        bool val = j < full;
        int s = __shfl(sv, j < 64 ? j : 0);
        const unsigned short* r = h2r + (size_t)s * 20;
        float w = val ? __expf(lrelu(h2f(r[16]) + ad)) : 0.f;
        unsigned int gp = *(const unsigned int*)(r + p * 2);
        den += w;
        accx += w * h2f((unsigned short)(gp & 0xffff));
        accy += w * h2f((unsigned short)(gp >> 16));
    }
    // tail for deg > 64 (essentially never)
    for (int base = 64; base < dg; base += 8) {
        int j = base + sub;
        bool val = j < dg;
        int s = csr[start + (val ? j : 0)];
        const unsigned short* r = h2r + (size_t)s * 20;
        float w = val ? __expf(lrelu(h2f(r[16]) + ad)) : 0.f;
        unsigned int gp = *(const unsigned int*)(r + p * 2);
        den += w;
        accx += w * h2f((unsigned short)(gp & 0xffff));
        accy += w * h2f((unsigned short)(gp >> 16));
    }
    accx += __shfl_xor(accx, 8); accx += __shfl_xor(accx, 16); accx += __shfl_xor(accx, 32);
    accy += __shfl_xor(accy, 8); accy += __shfl_xor(accy, 16); accy += __shfl_xor(accy, 32);
    den  += __shfl_xor(den, 8);  den  += __shfl_xor(den, 16);  den  += __shfl_xor(den, 32);
    if (sub == 0) {
        float inv = 1.f / (den + 1e-16f);
        ((float2*)out2)[(size_t)d * 8 + p] = make_float2(accx * inv, accy * inv);
    }
}

// -------- final: out[n,2] = concat_g(out2[g,n,:]+b2) @ Wf + bf --------------
__global__ __launch_bounds__(256) void k_final(const float* __restrict__ agg2,
                                               const float* __restrict__ b2,
                                               const float* __restrict__ Wf,
                                               const float* __restrict__ bf,
                                               float* __restrict__ out) {
    int n = blockIdx.x * 256 + threadIdx.x;
    if (n >= N_NODES) return;
    float o0 = bf[0], o1 = bf[1];
#pragma unroll
    for (int g = 0; g < G; ++g) {
        const float4* v4 = (const float4*)agg2 + (size_t)(g * N_NODES + n) * 4;
#pragma unroll
        for (int q = 0; q < 4; ++q) {
            float4 v = v4[q];
            float4 b = ((const float4*)b2)[q];
            v.x += b.x; v.y += b.y; v.z += b.z; v.w += b.w;
            int kb = g * 16 + q * 4;
            o0 += v.x * Wf[(kb + 0) * 2]     + v.y * Wf[(kb + 1) * 2]
                + v.z * Wf[(kb + 2) * 2]     + v.w * Wf[(kb + 3) * 2];
            o1 += v.x * Wf[(kb + 0) * 2 + 1] + v.y * Wf[(kb + 1) * 2 + 1]
                + v.z * Wf[(kb + 2) * 2 + 1] + v.w * Wf[(kb + 3) * 2 + 1];
        }
    }
    out[n * 2]     = o0;
    out[n * 2 + 1] = o1;
}

extern "C" void kernel_launch(void* const* d_in, const int* in_sizes, int n_in,
                              void* d_out, int out_size, void* d_ws, size_t ws_size,
                              hipStream_t stream) {
    const float* x      = (const float*)d_in[0];
    const int*   ei     = (const int*)d_in[1];
    const float* W1     = (const float*)d_in[2];
    const float* a_src1 = (const float*)d_in[3];
    const float* a_dst1 = (const float*)d_in[4];
    const float* b1     = (const float*)d_in[5];
    const float* W2     = (const float*)d_in[6];
    const float* a_src2 = (const float*)d_in[7];
    const float* a_dst2 = (const float*)d_in[8];
    const float* b2     = (const float*)d_in[9];
    const float* Wf     = (const float*)d_in[10];
    const float* bf     = (const float*)d_in[11];
    float* out = (float*)d_out;

    // workspace layout (lifetime aliasing):
    //   region A (36 MB): h1f[GN*64 u16] + l1[GN*8 u16]   (gemm1 -> layer1)
    //                     -> h2r[GN*20 u16] + out2[GN*16 f32]
    //   region B (32 MB): out1h[GN*64 u16]                (layer1 -> gemm2)
    //   region C (8 MB):  ad1[GN*8 f32] -> ad2[GN f32]
    //   ints: rowptr, deg, base_g, T, H, tmp, csr
    //   tail: W1^T hi/lo fp16 (32 KB)
    unsigned short* h1f = (unsigned short*)d_ws;             // GN*64 u16 (128B rows)
    unsigned short* l1  = h1f + (size_t)GN * 64;             // GN*8 u16
    unsigned short* h2r = h1f;                               // GN*20 u16 (alias)
    float* out2 = (float*)(h2r + (size_t)GN * 20);           // GN*16 f32 (alias; 8B-aligned)
    unsigned short* out1h = h1f + (size_t)GN * 72;           // GN*64 u16
    float* ad1  = (float*)(out1h + (size_t)GN * 64);         // GN*8 f32
    float* ad2  = ad1;                                       // GN (alias)
    int*   iws    = (int*)(ad1 + (size_t)GN * 8);
    int*   rowptr = iws;                                     // GN
    int*   deg    = rowptr + GN;                             // GN
    int*   base_g = deg + GN;                                // NBUK+1
    int*   T      = base_g + (NBUK + 1);                     // NBUK
    int*   H      = T + NBUK;                                // NBLK_E*NBUK
    int*   tmp    = H + (size_t)NBLK_E * NBUK;               // GE
    int*   csr    = tmp + GE;                                // GE
    uintptr_t wp = ((uintptr_t)(csr + GE) + 15) & ~(uintptr_t)15;
    f16* WhT = (f16*)wp;                                     // 64*128 f16
    f16* WlT = WhT + 64 * 128;                               // 64*128 f16

    // CSR build via bucket sort (no global atomics, coalesced writes)
    k_hist   <<<NBLK_E, 256, 0, stream>>>(ei, H);
    k_scanH  <<<NBUK,   256, 0, stream>>>(H, T);
    k_scanT  <<<1,      256, 0, stream>>>(T, base_g);
    k_scatter<<<NBLK_E, 256, 0, stream>>>(ei, H, base_g, tmp);
    k_build  <<<NBUK,   256, 0, stream>>>(base_g, tmp, rowptr, deg, csr);

    k_prepW  <<<32, 256, 0, stream>>>(W1, WhT, WlT);
    k_gemm1  <<<(GN + 127) / 128, 256, 0, stream>>>(x, WhT, WlT, a_src1, a_dst1, h1f, l1, ad1);
    k_layer1 <<<GN / 8, 256, 0, stream>>>(rowptr, deg, csr, h1f, l1, ad1, out1h);
    k_gemm2  <<<(GN + 63) / 64, 256, 0, stream>>>(out1h, b1, W2, a_src2, a_dst2, h2r, ad2);
    k_layer2 <<<GN / 4, 256, 0, stream>>>(rowptr, deg, csr, h2r, ad2, out2);
    k_final  <<<(N_NODES + 255) / 256, 256, 0, stream>>>(out2, b2, Wf, bf, out);
}

// Round 5
// 527.431 us; speedup vs baseline: 1.1094x; 1.0188x over previous
//
#include <hip/hip_runtime.h>

// Problem constants (fixed by the reference setup)
constexpr int N_NODES = 50000;
constexpr int G = 5;
constexpr int E = 850000;            // E0 (800000) + N self-loops
constexpr int GN = G * N_NODES;      // 250000
constexpr int GE = G * E;            // 4,250,000
constexpr float SLOPE = 0.2f;

// Bucket sort parameters
constexpr int NPB = 1024;                        // nodes per bucket
constexpr int NBUK = (GN + NPB - 1) / NPB;       // 245
constexpr int EPB = 4096;                        // edges per block (256 thr x 16)
constexpr int NBLK_E = (GE + EPB - 1) / EPB;     // 1038

typedef _Float16 f16;
typedef f16 f16x4 __attribute__((ext_vector_type(4)));
typedef float f32x4 __attribute__((ext_vector_type(4)));

static __device__ __forceinline__ float lrelu(float e) {
    return e > 0.f ? e : SLOPE * e;
}
static __device__ __forceinline__ unsigned short f2h(float f) {
    union { _Float16 h; unsigned short u; } v;
    v.h = (_Float16)f;
    return v.u;
}
static __device__ __forceinline__ float h2f(unsigned short u) {
    union { unsigned short u; _Float16 h; } v;
    v.u = u;
    return (float)v.h;
}
static __device__ __forceinline__ f16x4 u2h4(uint2 u) {
    union { uint2 u; f16x4 h; } c;
    c.u = u;
    return c.h;
}

// ---------------- pass A1: per-block bucket histogram -----------------------
__global__ __launch_bounds__(256) void k_hist(const int* __restrict__ ei,
                                              int* __restrict__ H) {
    __shared__ int hist[NBUK];
    const int t = threadIdx.x, bi = blockIdx.x;
    for (int j = t; j < NBUK; j += 256) hist[j] = 0;
    __syncthreads();
#pragma unroll
    for (int i = 0; i < 16; ++i) {
        int idx = bi * EPB + i * 256 + t;
        if (idx < GE) {
            int g = idx / E;
            int el = idx - g * E;
            int dst = ei[(size_t)g * 2 * E + E + el];
            atomicAdd(&hist[(g * N_NODES + dst) >> 10], 1);
        }
    }
    __syncthreads();
    for (int j = t; j < NBUK; j += 256) H[(size_t)bi * NBUK + j] = hist[j];
}

// ------- pass A2a: per bucket, exclusive scan of H over blocks; totals ------
__global__ __launch_bounds__(256) void k_scanH(int* __restrict__ H,
                                               int* __restrict__ T) {
    __shared__ int s[256];
    const int t = threadIdx.x, b = blockIdx.x;
    int run = 0;
    for (int c = 0; c < NBLK_E; c += 256) {
        int bi = c + t;
        int v = (bi < NBLK_E) ? H[(size_t)bi * NBUK + b] : 0;
        s[t] = v;
        for (int off = 1; off < 256; off <<= 1) {
            __syncthreads();
            int u = (t >= off) ? s[t - off] : 0;
            __syncthreads();
            s[t] += u;
        }
        __syncthreads();
        int excl = s[t] - v;
        if (bi < NBLK_E) H[(size_t)bi * NBUK + b] = run + excl;
        run += s[255];
        __syncthreads();
    }
    if (t == 0) T[b] = run;
}

// ------- pass A2b: exclusive scan of bucket totals -> bucket bases ----------
__global__ __launch_bounds__(256) void k_scanT(const int* __restrict__ T,
                                               int* __restrict__ base_g) {
    __shared__ int s[256];
    const int t = threadIdx.x;
    int v = (t < NBUK) ? T[t] : 0;
    s[t] = v;
    for (int off = 1; off < 256; off <<= 1) {
        __syncthreads();
        int u = (t >= off) ? s[t - off] : 0;
        __syncthreads();
        s[t] += u;
    }
    __syncthreads();
    if (t < NBUK) base_g[t] = s[t] - v;
    if (t == 0) base_g[NBUK] = s[255];
}

// ------- pass A3: scatter packed (dstLow10<<18 | src) into bucket groups ----
__global__ __launch_bounds__(256) void k_scatter(const int* __restrict__ ei,
                                                 const int* __restrict__ H,
                                                 const int* __restrict__ base_g,
                                                 int* __restrict__ tmp) {
    __shared__ int cnt[NBUK];
    __shared__ int off[NBUK];
    const int t = threadIdx.x, bi = blockIdx.x;
    for (int j = t; j < NBUK; j += 256) {
        cnt[j] = 0;
        off[j] = base_g[j] + H[(size_t)bi * NBUK + j];
    }
    __syncthreads();
#pragma unroll
    for (int i = 0; i < 16; ++i) {
        int idx = bi * EPB + i * 256 + t;
        if (idx < GE) {
            int g = idx / E;
            int el = idx - g * E;
            const int* eb = ei + (size_t)g * 2 * E;
            int src = eb[el];
            int dst = eb[E + el];
            int gdst = g * N_NODES + dst;
            int b = gdst >> 10;
            int rank = atomicAdd(&cnt[b], 1);
            tmp[off[b] + rank] = ((gdst & 1023) << 18) | (g * N_NODES + src);
        }
    }
}

// ------- pass B: per-bucket LDS counting sort -> rowptr/deg/csr -------------
__global__ __launch_bounds__(256) void k_build(const int* __restrict__ base_g,
                                               const int* __restrict__ tmp,
                                               int* __restrict__ rowptr,
                                               int* __restrict__ deg,
                                               int* __restrict__ csr) {
    __shared__ int degL[NPB];
    __shared__ int curL[NPB];
    __shared__ int s[256];
    const int t = threadIdx.x, b = blockIdx.x;
    const int n0 = b << 10;
    const int nn = min(NPB, GN - n0);
    const int s0 = base_g[b], s1 = base_g[b + 1];
#pragma unroll
    for (int i = 0; i < 4; ++i) degL[t * 4 + i] = 0;
    __syncthreads();
    for (int i = s0 + t; i < s1; i += 256)
        atomicAdd(&degL[tmp[i] >> 18], 1);
    __syncthreads();
    int j0 = t * 4;
    int d0 = degL[j0], d1 = degL[j0 + 1], d2 = degL[j0 + 2], d3 = degL[j0 + 3];
    int tsum = d0 + d1 + d2 + d3;
    s[t] = tsum;
    for (int off = 1; off < 256; off <<= 1) {
        __syncthreads();
        int u = (t >= off) ? s[t - off] : 0;
        __syncthreads();
        s[t] += u;
    }
    __syncthreads();
    int excl = s[t] - tsum;
    int p0 = excl, p1 = p0 + d0, p2 = p1 + d1, p3 = p2 + d2;
    curL[j0] = p0; curL[j0 + 1] = p1; curL[j0 + 2] = p2; curL[j0 + 3] = p3;
    if (j0     < nn) { rowptr[n0 + j0]     = s0 + p0; deg[n0 + j0]     = d0; }
    if (j0 + 1 < nn) { rowptr[n0 + j0 + 1] = s0 + p1; deg[n0 + j0 + 1] = d1; }
    if (j0 + 2 < nn) { rowptr[n0 + j0 + 2] = s0 + p2; deg[n0 + j0 + 2] = d2; }
    if (j0 + 3 < nn) { rowptr[n0 + j0 + 3] = s0 + p3; deg[n0 + j0 + 3] = d3; }
    __syncthreads();
    for (int i = s0 + t; i < s1; i += 256) {
        int e = tmp[i];
        int r = atomicAdd(&curL[e >> 18], 1);
        csr[s0 + r] = e & 0x3FFFF;
    }
}

// ------- prep: W1 (128x64 f32, k-major) -> W1^T hi/lo f16 [64][128] ---------
__global__ __launch_bounds__(256) void k_prepW(const float* __restrict__ W1,
                                               f16* __restrict__ WhT,
                                               f16* __restrict__ WlT) {
    int t = blockIdx.x * 256 + threadIdx.x;   // 8192 elements
    if (t >= 128 * 64) return;
    int k = t & 127;          // consecutive threads -> consecutive k (coalesced writes)
    int n = t >> 7;
    float w = W1[k * 64 + n];
    f16 h = (f16)w;
    WhT[n * 128 + k] = h;
    WlT[n * 128 + k] = (f16)(w - (float)h);
}

// --- GEMM1 via MFMA (split-fp16 for fp32 accuracy) + fused logits -----------
__global__ __launch_bounds__(256, 3) void k_gemm1(const float* __restrict__ x,
                                               const f16* __restrict__ WhT,
                                               const f16* __restrict__ WlT,
                                               const float* __restrict__ a_src,
                                               const float* __restrict__ a_dst,
                                               unsigned short* __restrict__ h1f,
                                               unsigned short* __restrict__ l1,
                                               float* __restrict__ ad1) {
    __shared__ uint4 Bls[2048];               // 32 KB: slot kc*64 + (col^(kc&3))
    const int t = threadIdx.x;
    const int lane = t & 63;
    const int wv = t >> 6;
    const int ln15 = lane & 15;
    const int q = lane >> 4;                  // quarter-wave: k-group
    const int rowBase = blockIdx.x * 128 + wv * 32;

    // ---- A loads: 2 Mtiles x 8 Ksteps x (4 consecutive fp32), held in regs ----
    const float4* x4 = (const float4*)x;
    float4 araw[2][8];
#pragma unroll
    for (int m = 0; m < 2; ++m) {
        int row = rowBase + m * 16 + ln15;
        row = row < GN ? row : GN - 1;        // clamp (pad rows compute garbage)
        const float4* xr = x4 + (size_t)row * 32 + q;
#pragma unroll
        for (int s = 0; s < 8; ++s)
            araw[m][s] = xr[s * 4];           // k = s*16 + q*4 .. +3
    }

    // ---- stage B into LDS (coalesced linear reads, swizzled writes) ----
    const uint2* WhT2 = (const uint2*)WhT;    // v-th 8B chunk = W col v>>5, k (v&31)*4
    const uint2* WlT2 = (const uint2*)WlT;
#pragma unroll
    for (int i = 0; i < 8; ++i) {
        int v = t + i * 256;                  // 0..2047
        int col = v >> 5, kc = v & 31;
        uint2 bh = WhT2[v];
        uint2 bl = WlT2[v];
        Bls[kc * 64 + (col ^ (kc & 3))] = make_uint4(bh.x, bh.y, bl.x, bl.y);
    }
    __syncthreads();

    f32x4 acc[2][4];
#pragma unroll
    for (int m = 0; m < 2; ++m)
#pragma unroll
        for (int nt = 0; nt < 4; ++nt)
            acc[m][nt] = (f32x4){0.f, 0.f, 0.f, 0.f};

#pragma unroll
    for (int s = 0; s < 8; ++s) {
        // B fragments: lane holds W1[k = s*16 + q*4 + j][col = nt*16 + ln15]
        f16x4 bh[4], bl[4];
#pragma unroll
        for (int nt = 0; nt < 4; ++nt) {
            uint4 b = Bls[(s * 4 + q) * 64 + ((nt * 16 + ln15) ^ q)];
            bh[nt] = u2h4(make_uint2(b.x, b.y));
            bl[nt] = u2h4(make_uint2(b.z, b.w));
        }
#pragma unroll
        for (int m = 0; m < 2; ++m) {
            float4 r = araw[m][s];
            f16 h0 = (f16)r.x, h1 = (f16)r.y, h2 = (f16)r.z, h3 = (f16)r.w;
            f16x4 ah = {h0, h1, h2, h3};
            f16x4 al = {(f16)(r.x - (float)h0), (f16)(r.y - (float)h1),
                        (f16)(r.z - (float)h2), (f16)(r.w - (float)h3)};
#pragma unroll
            for (int nt = 0; nt < 4; ++nt) {
                acc[m][nt] = __builtin_amdgcn_mfma_f32_16x16x16f16(ah, bh[nt], acc[m][nt], 0, 0, 0);
                acc[m][nt] = __builtin_amdgcn_mfma_f32_16x16x16f16(al, bh[nt], acc[m][nt], 0, 0, 0);
                acc[m][nt] = __builtin_amdgcn_mfma_f32_16x16x16f16(ah, bl[nt], acc[m][nt], 0, 0, 0);
            }
        }
    }

    // ---- epilogue: C[row][col], col = nt*16 + ln15, row = base + q*4 + i ----
    float aSv[4], aDv[4];
#pragma unroll
    for (int nt = 0; nt < 4; ++nt) {
        aSv[nt] = a_src[nt * 16 + ln15];
        aDv[nt] = a_dst[nt * 16 + ln15];
    }
#pragma unroll
    for (int m = 0; m < 2; ++m) {
#pragma unroll
        for (int i = 0; i < 4; ++i) {
            int row = rowBase + m * 16 + q * 4 + i;
            bool ok = row < GN;
#pragma unroll
            for (int nt = 0; nt < 4; ++nt) {
                float v = acc[m][nt][i];
                if (ok) h1f[(size_t)row * 64 + nt * 16 + ln15] = f2h(v);
                float ps = v * aSv[nt];
                float pd = v * aDv[nt];
                ps += __shfl_xor(ps, 1); ps += __shfl_xor(ps, 2); ps += __shfl_xor(ps, 4);
                pd += __shfl_xor(pd, 1); pd += __shfl_xor(pd, 2); pd += __shfl_xor(pd, 4);
                if (ok && (ln15 & 7) == 0) {
                    int head = nt * 2 + (ln15 >> 3);
                    l1[(size_t)row * 8 + head] = f2h(ps);
                    ad1[row * 8 + head] = pd;
                }
            }
        }
    }
}

// ------- layer-1 gather: 2 dsts/wave; adjacency in regs + 1-deep pipeline ---
// Per 32-lane half: 4 edge-slots x 8 heads. Whole adjacency row (deg<=32) is
// loaded once into sv (per-lane), s comes from shfl; l1/h1f gathers for
// iteration k+1 are issued before processing iteration k.
__global__ __launch_bounds__(256) void k_layer1(const int* __restrict__ rowptr,
                                                const int* __restrict__ deg,
                                                const int* __restrict__ csr,
                                                const unsigned short* __restrict__ h1f,
                                                const unsigned short* __restrict__ l1,
                                                const float* __restrict__ ad1,
                                                unsigned short* __restrict__ out1h) {
    const int tt = threadIdx.x & 63;
    const int h  = tt & 7;            // head (8 channels each)
    const int es = (tt >> 3) & 3;     // edge slot within dst
    const int hb = tt & 32;           // base lane of this half
    const int d  = blockIdx.x * 8 + (threadIdx.x >> 5);   // dst node (2 per wave)

    const int start = rowptr[d];
    const int dg    = deg[d];
    const float ad  = ad1[d * 8 + h];

    const int q5 = tt & 31;
    const int sv = csr[start + min(q5, dg - 1)];          // adjacency row in regs

    const unsigned int* h1d = (const unsigned int*)h1f;   // row = 32 dwords
    float a0 = 0.f, a1 = 0.f, a2 = 0.f, a3 = 0.f;
    float a4 = 0.f, a5 = 0.f, a6 = 0.f, a7 = 0.f;
    float den = 0.f;

    const int limit = min(dg, 32);
    union C { uint4 u; f16 hh[8]; };

    // prologue: issue loads for slot 0
    bool val = es < limit;
    int s = __shfl(sv, hb + (val ? es : 0));
    unsigned short lv = l1[(size_t)s * 8 + h];
    C c; c.u = *(const uint4*)(h1d + (size_t)s * 32 + h * 4);

    for (int base = 4; base < limit + 4; base += 4) {
        // issue next iteration's loads first (latency overlap)
        bool val2 = false; unsigned short lv2 = 0; C c2;
        c2.u = make_uint4(0, 0, 0, 0);
        if (base < limit) {
            int j2 = base + es;
            val2 = j2 < limit;
            int s2 = __shfl(sv, hb + (val2 ? j2 : 0));
            lv2 = l1[(size_t)s2 * 8 + h];
            c2.u = *(const uint4*)(h1d + (size_t)s2 * 32 + h * 4);
        }
        // process current
        float w = val ? __expf(lrelu(h2f(lv) + ad)) : 0.f;
        den += w;
        a0 += w * (float)c.hh[0];
        a1 += w * (float)c.hh[1];
        a2 += w * (float)c.hh[2];
        a3 += w * (float)c.hh[3];
        a4 += w * (float)c.hh[4];
        a5 += w * (float)c.hh[5];
        a6 += w * (float)c.hh[6];
        a7 += w * (float)c.hh[7];
        val = val2; lv = lv2; c = c2;
    }

    // rare tail: deg > 32 (direct csr reads, old path)
    for (int j = 32 + es; j < dg; j += 4) {
        int s3 = csr[start + j];
        float w = __expf(lrelu(h2f(l1[(size_t)s3 * 8 + h]) + ad));
        den += w;
        C c3; c3.u = *(const uint4*)(h1d + (size_t)s3 * 32 + h * 4);
        a0 += w * (float)c3.hh[0];
        a1 += w * (float)c3.hh[1];
        a2 += w * (float)c3.hh[2];
        a3 += w * (float)c3.hh[3];
        a4 += w * (float)c3.hh[4];
        a5 += w * (float)c3.hh[5];
        a6 += w * (float)c3.hh[6];
        a7 += w * (float)c3.hh[7];
    }

    a0 += __shfl_xor(a0, 8);  a0 += __shfl_xor(a0, 16);
    a1 += __shfl_xor(a1, 8);  a1 += __shfl_xor(a1, 16);
    a2 += __shfl_xor(a2, 8);  a2 += __shfl_xor(a2, 16);
    a3 += __shfl_xor(a3, 8);  a3 += __shfl_xor(a3, 16);
    a4 += __shfl_xor(a4, 8);  a4 += __shfl_xor(a4, 16);
    a5 += __shfl_xor(a5, 8);  a5 += __shfl_xor(a5, 16);
    a6 += __shfl_xor(a6, 8);  a6 += __shfl_xor(a6, 16);
    a7 += __shfl_xor(a7, 8);  a7 += __shfl_xor(a7, 16);
    den += __shfl_xor(den, 8); den += __shfl_xor(den, 16);

    if (es == 0) {
        float inv = 1.f / (den + 1e-16f);
        unsigned int p0 = (unsigned int)f2h(a0 * inv) | ((unsigned int)f2h(a1 * inv) << 16);
        unsigned int p1 = (unsigned int)f2h(a2 * inv) | ((unsigned int)f2h(a3 * inv) << 16);
        unsigned int p2 = (unsigned int)f2h(a4 * inv) | ((unsigned int)f2h(a5 * inv) << 16);
        unsigned int p3 = (unsigned int)f2h(a6 * inv) | ((unsigned int)f2h(a7 * inv) << 16);
        *(uint4*)(out1h + (size_t)d * 64 + h * 8) = make_uint4(p0, p1, p2, p3);
    }
}

// --- GEMM2 + fused logits: h2r[GN][20] fp16 (16 ch + logit in one 40B row) --
__global__ __launch_bounds__(256) void k_gemm2(const unsigned short* __restrict__ agg1,
                                               const float* __restrict__ b1,
                                               const float* __restrict__ W2,
                                               const float* __restrict__ a_src,
                                               const float* __restrict__ a_dst,
                                               unsigned short* __restrict__ h2r,
                                               float* __restrict__ ad2) {
    __shared__ float As[64][65];
    __shared__ float Bs[64][20];
    __shared__ float aS[16], aD[16];
    const int t = threadIdx.x;
    const int rowBase = blockIdx.x * 64;

    {
        int k = t >> 2, c = (t & 3) << 2;
        float4 w = ((const float4*)W2)[t];
        Bs[k][c] = w.x; Bs[k][c + 1] = w.y; Bs[k][c + 2] = w.z; Bs[k][c + 3] = w.w;
    }
    if (t < 16) { aS[t] = a_src[t]; aD[t] = a_dst[t]; }
    const ushort4* a4p = (const ushort4*)agg1;
    const float4* b14 = (const float4*)b1;
#pragma unroll
    for (int i = 0; i < 4; ++i) {
        int v = t + i * 256;
        int r = v >> 4;
        int kq = v & 15;
        int row = rowBase + r;
        float ax = 0.f, ay = 0.f, az = 0.f, aw = 0.f;
        if (row < GN) {
            ushort4 a = a4p[row * 16 + kq];
            float4 bb = b14[kq];
            ax = fmaxf(h2f(a.x) + bb.x, 0.f);
            ay = fmaxf(h2f(a.y) + bb.y, 0.f);
            az = fmaxf(h2f(a.z) + bb.z, 0.f);
            aw = fmaxf(h2f(a.w) + bb.w, 0.f);
        }
        int kk = kq << 2;
        As[kk][r] = ax; As[kk + 1][r] = ay; As[kk + 2][r] = az; As[kk + 3][r] = aw;
    }
    __syncthreads();
    const int r = t >> 2;
    const int cg = (t & 3) << 2;
    float acc0 = 0.f, acc1 = 0.f, acc2 = 0.f, acc3 = 0.f;
#pragma unroll 8
    for (int k = 0; k < 64; ++k) {
        float a = As[k][r];
        float4 b = *(const float4*)&Bs[k][cg];
        acc0 += a * b.x; acc1 += a * b.y; acc2 += a * b.z; acc3 += a * b.w;
    }
    float as_p = acc0 * aS[cg] + acc1 * aS[cg + 1] + acc2 * aS[cg + 2] + acc3 * aS[cg + 3];
    float ad_p = acc0 * aD[cg] + acc1 * aD[cg + 1] + acc2 * aD[cg + 2] + acc3 * aD[cg + 3];
    as_p += __shfl_xor(as_p, 1); as_p += __shfl_xor(as_p, 2);
    ad_p += __shfl_xor(ad_p, 1); ad_p += __shfl_xor(ad_p, 2);
    int row = rowBase + r;
    if (row < GN) {
        ushort4 fv = make_ushort4(f2h(acc0), f2h(acc1), f2h(acc2), f2h(acc3));
        *(ushort4*)(h2r + (size_t)row * 20 + cg) = fv;   // row*40B + cg*2 is 8B-aligned
        if ((t & 3) == 0) {
            h2r[(size_t)row * 20 + 16] = f2h(as_p);
            ad2[row] = ad_p;
        }
    }
}

// ------- layer-2 gather: one wave/dst, 8 edge-slots x 8 ch-pairs ------------
__global__ __launch_bounds__(256) void k_layer2(const int* __restrict__ rowptr,
                                                const int* __restrict__ deg,
                                                const int* __restrict__ csr,
                                                const unsigned short* __restrict__ h2r,
                                                const float* __restrict__ ad2,
                                                float* __restrict__ out2) {
    int d = __builtin_amdgcn_readfirstlane(blockIdx.x * 4 + (threadIdx.x >> 6));
    int tt = threadIdx.x & 63;
    int p = tt & 7;                   // channel pair (ch 2p, 2p+1)
    int sub = tt >> 3;                // 8 edge slots
    int start = rowptr[d];
    int dg = deg[d];
    float ad = ad2[d];
    int sv = csr[start + min(tt, dg - 1)];   // whole adjacency in registers
    int full = min(dg, 64);
    float den = 0.f, accx = 0.f, accy = 0.f;
    for (int base = 0; base < full; base += 8) {
        int j = base + sub;
        bool val = j < full;
        int s = __shfl(sv, j < 64 ? j : 0);
        const unsigned short* r = h2r + (size_t)s * 20;
        float w = val ? __expf(lrelu(h2f(r[16]) + ad)) : 0.f;
        unsigned int gp = *(const unsigned int*)(r + p * 2);
        den += w;
        accx += w * h2f((unsigned short)(gp & 0xffff));
        accy += w * h2f((unsigned short)(gp >> 16));
    }
    // tail for deg > 64 (essentially never)
    for (int base = 64; base < dg; base += 8) {
        int j = base + sub;
        bool val = j < dg;
        int s = csr[start + (val ? j : 0)];
        const unsigned short* r = h2r + (size_t)s * 20;
        float w = val ? __expf(lrelu(h2f(r[16]) + ad)) : 0.f;
        unsigned int gp = *(const unsigned int*)(r + p * 2);
        den += w;
        accx += w * h2f((unsigned short)(gp & 0xffff));
        accy += w * h2f((unsigned short)(gp >> 16));
    }
    accx += __shfl_xor(accx, 8); accx += __shfl_xor(accx, 16); accx += __shfl_xor(accx, 32);
    accy += __shfl_xor(accy, 8); accy += __shfl_xor(accy, 16); accy += __shfl_xor(accy, 32);
    den  += __shfl_xor(den, 8);  den  += __shfl_xor(den, 16);  den  += __shfl_xor(den, 32);
    if (sub == 0) {
        float inv = 1.f / (den + 1e-16f);
        ((float2*)out2)[(size_t)d * 8 + p] = make_float2(accx * inv, accy * inv);
    }
}

// -------- final: out[n,2] = concat_g(out2[g,n,:]+b2) @ Wf + bf --------------
__global__ __launch_bounds__(256) void k_final(const float* __restrict__ agg2,
                                               const float* __restrict__ b2,
                                               const float* __restrict__ Wf,
                                               const float* __restrict__ bf,
                                               float* __restrict__ out) {
    int n = blockIdx.x * 256 + threadIdx.x;
    if (n >= N_NODES) return;
    float o0 = bf[0], o1 = bf[1];
#pragma unroll
    for (int g = 0; g < G; ++g) {
        const float4* v4 = (const float4*)agg2 + (size_t)(g * N_NODES + n) * 4;
#pragma unroll
        for (int q = 0; q < 4; ++q) {
            float4 v = v4[q];
            float4 b = ((const float4*)b2)[q];
            v.x += b.x; v.y += b.y; v.z += b.z; v.w += b.w;
            int kb = g * 16 + q * 4;
            o0 += v.x * Wf[(kb + 0) * 2]     + v.y * Wf[(kb + 1) * 2]
                + v.z * Wf[(kb + 2) * 2]     + v.w * Wf[(kb + 3) * 2];
            o1 += v.x * Wf[(kb + 0) * 2 + 1] + v.y * Wf[(kb + 1) * 2 + 1]
                + v.z * Wf[(kb + 2) * 2 + 1] + v.w * Wf[(kb + 3) * 2 + 1];
        }
    }
    out[n * 2]     = o0;
    out[n * 2 + 1] = o1;
}

extern "C" void kernel_launch(void* const* d_in, const int* in_sizes, int n_in,
                              void* d_out, int out_size, void* d_ws, size_t ws_size,
                              hipStream_t stream) {
    const float* x      = (const float*)d_in[0];
    const int*   ei     = (const int*)d_in[1];
    const float* W1     = (const float*)d_in[2];
    const float* a_src1 = (const float*)d_in[3];
    const float* a_dst1 = (const float*)d_in[4];
    const float* b1     = (const float*)d_in[5];
    const float* W2     = (const float*)d_in[6];
    const float* a_src2 = (const float*)d_in[7];
    const float* a_dst2 = (const float*)d_in[8];
    const float* b2     = (const float*)d_in[9];
    const float* Wf     = (const float*)d_in[10];
    const float* bf     = (const float*)d_in[11];
    float* out = (float*)d_out;

    // workspace layout (lifetime aliasing):
    //   region A (36 MB): h1f[GN*64 u16] + l1[GN*8 u16]   (gemm1 -> layer1)
    //                     -> h2r[GN*20 u16] + out2[GN*16 f32]
    //   region B (32 MB): out1h[GN*64 u16]                (layer1 -> gemm2)
    //   region C (8 MB):  ad1[GN*8 f32] -> ad2[GN f32]
    //   ints: rowptr, deg, base_g, T, H, tmp, csr
    //   tail: W1^T hi/lo fp16 (32 KB)
    unsigned short* h1f = (unsigned short*)d_ws;             // GN*64 u16 (128B rows)
    unsigned short* l1  = h1f + (size_t)GN * 64;             // GN*8 u16
    unsigned short* h2r = h1f;                               // GN*20 u16 (alias)
    float* out2 = (float*)(h2r + (size_t)GN * 20);           // GN*16 f32 (alias; 8B-aligned)
    unsigned short* out1h = h1f + (size_t)GN * 72;           // GN*64 u16
    float* ad1  = (float*)(out1h + (size_t)GN * 64);         // GN*8 f32
    float* ad2  = ad1;                                       // GN (alias)
    int*   iws    = (int*)(ad1 + (size_t)GN * 8);
    int*   rowptr = iws;                                     // GN
    int*   deg    = rowptr + GN;                             // GN
    int*   base_g = deg + GN;                                // NBUK+1
    int*   T      = base_g + (NBUK + 1);                     // NBUK
    int*   H      = T + NBUK;                                // NBLK_E*NBUK
    int*   tmp    = H + (size_t)NBLK_E * NBUK;               // GE
    int*   csr    = tmp + GE;                                // GE
    uintptr_t wp = ((uintptr_t)(csr + GE) + 15) & ~(uintptr_t)15;
    f16* WhT = (f16*)wp;                                     // 64*128 f16
    f16* WlT = WhT + 64 * 128;                               // 64*128 f16

    // CSR build via bucket sort (no global atomics, coalesced writes)
    k_hist   <<<NBLK_E, 256, 0, stream>>>(ei, H);
    k_scanH  <<<NBUK,   256, 0, stream>>>(H, T);
    k_scanT  <<<1,      256, 0, stream>>>(T, base_g);
    k_scatter<<<NBLK_E, 256, 0, stream>>>(ei, H, base_g, tmp);
    k_build  <<<NBUK,   256, 0, stream>>>(base_g, tmp, rowptr, deg, csr);

    k_prepW  <<<32, 256, 0, stream>>>(W1, WhT, WlT);
    k_gemm1  <<<(GN + 127) / 128, 256, 0, stream>>>(x, WhT, WlT, a_src1, a_dst1, h1f, l1, ad1);
    k_layer1 <<<GN / 8, 256, 0, stream>>>(rowptr, deg, csr, h1f, l1, ad1, out1h);
    k_gemm2  <<<(GN + 63) / 64, 256, 0, stream>>>(out1h, b1, W2, a_src2, a_dst2, h2r, ad2);
    k_layer2 <<<GN / 4, 256, 0, stream>>>(rowptr, deg, csr, h2r, ad2, out2);
    k_final  <<<(N_NODES + 255) / 256, 256, 0, stream>>>(out2, b2, Wf, bf, out);
}

// Round 6
// 519.092 us; speedup vs baseline: 1.1272x; 1.0161x over previous
//
#include <hip/hip_runtime.h>

// Problem constants (fixed by the reference setup)
constexpr int N_NODES = 50000;
constexpr int G = 5;
constexpr int E = 850000;            // E0 (800000) + N self-loops
constexpr int GN = G * N_NODES;      // 250000
constexpr int GE = G * E;            // 4,250,000
constexpr float SLOPE = 0.2f;

// Bucket sort parameters
constexpr int NPB = 1024;                        // nodes per bucket
constexpr int NBUK = (GN + NPB - 1) / NPB;       // 245
constexpr int EPB = 4096;                        // edges per block (256 thr x 16)
constexpr int NBLK_E = (GE + EPB - 1) / EPB;     // 1038

typedef _Float16 f16;
typedef f16 f16x4 __attribute__((ext_vector_type(4)));
typedef float f32x4 __attribute__((ext_vector_type(4)));

static __device__ __forceinline__ float lrelu(float e) {
    return e > 0.f ? e : SLOPE * e;
}
static __device__ __forceinline__ unsigned short f2h(float f) {
    union { _Float16 h; unsigned short u; } v;
    v.h = (_Float16)f;
    return v.u;
}
static __device__ __forceinline__ float h2f(unsigned short u) {
    union { unsigned short u; _Float16 h; } v;
    v.u = u;
    return (float)v.h;
}
static __device__ __forceinline__ f16x4 u2h4(uint2 u) {
    union { uint2 u; f16x4 h; } c;
    c.u = u;
    return c.h;
}

// ---------------- pass A1: per-block bucket histogram -----------------------
__global__ __launch_bounds__(256) void k_hist(const int* __restrict__ ei,
                                              int* __restrict__ H) {
    __shared__ int hist[NBUK];
    const int t = threadIdx.x, bi = blockIdx.x;
    for (int j = t; j < NBUK; j += 256) hist[j] = 0;
    __syncthreads();
#pragma unroll
    for (int i = 0; i < 16; ++i) {
        int idx = bi * EPB + i * 256 + t;
        if (idx < GE) {
            int g = idx / E;
            int el = idx - g * E;
            int dst = ei[(size_t)g * 2 * E + E + el];
            atomicAdd(&hist[(g * N_NODES + dst) >> 10], 1);
        }
    }
    __syncthreads();
    for (int j = t; j < NBUK; j += 256) H[(size_t)bi * NBUK + j] = hist[j];
}

// ------- pass A2a: per bucket, exclusive scan of H over blocks; totals ------
__global__ __launch_bounds__(256) void k_scanH(int* __restrict__ H,
                                               int* __restrict__ T) {
    __shared__ int s[256];
    const int t = threadIdx.x, b = blockIdx.x;
    int run = 0;
    for (int c = 0; c < NBLK_E; c += 256) {
        int bi = c + t;
        int v = (bi < NBLK_E) ? H[(size_t)bi * NBUK + b] : 0;
        s[t] = v;
        for (int off = 1; off < 256; off <<= 1) {
            __syncthreads();
            int u = (t >= off) ? s[t - off] : 0;
            __syncthreads();
            s[t] += u;
        }
        __syncthreads();
        int excl = s[t] - v;
        if (bi < NBLK_E) H[(size_t)bi * NBUK + b] = run + excl;
        run += s[255];
        __syncthreads();
    }
    if (t == 0) T[b] = run;
}

// ------- pass A2b: exclusive scan of bucket totals -> bucket bases ----------
__global__ __launch_bounds__(256) void k_scanT(const int* __restrict__ T,
                                               int* __restrict__ base_g) {
    __shared__ int s[256];
    const int t = threadIdx.x;
    int v = (t < NBUK) ? T[t] : 0;
    s[t] = v;
    for (int off = 1; off < 256; off <<= 1) {
        __syncthreads();
        int u = (t >= off) ? s[t - off] : 0;
        __syncthreads();
        s[t] += u;
    }
    __syncthreads();
    if (t < NBUK) base_g[t] = s[t] - v;
    if (t == 0) base_g[NBUK] = s[255];
}

// ------- pass A3: scatter packed (dstLow10<<18 | src) into bucket groups ----
__global__ __launch_bounds__(256) void k_scatter(const int* __restrict__ ei,
                                                 const int* __restrict__ H,
                                                 const int* __restrict__ base_g,
                                                 int* __restrict__ tmp) {
    __shared__ int cnt[NBUK];
    __shared__ int off[NBUK];
    const int t = threadIdx.x, bi = blockIdx.x;
    for (int j = t; j < NBUK; j += 256) {
        cnt[j] = 0;
        off[j] = base_g[j] + H[(size_t)bi * NBUK + j];
    }
    __syncthreads();
#pragma unroll
    for (int i = 0; i < 16; ++i) {
        int idx = bi * EPB + i * 256 + t;
        if (idx < GE) {
            int g = idx / E;
            int el = idx - g * E;
            const int* eb = ei + (size_t)g * 2 * E;
            int src = eb[el];
            int dst = eb[E + el];
            int gdst = g * N_NODES + dst;
            int b = gdst >> 10;
            int rank = atomicAdd(&cnt[b], 1);
            tmp[off[b] + rank] = ((gdst & 1023) << 18) | (g * N_NODES + src);
        }
    }
}

// ------- pass B: per-bucket LDS counting sort -> rowptr/deg/csr -------------
__global__ __launch_bounds__(256) void k_build(const int* __restrict__ base_g,
                                               const int* __restrict__ tmp,
                                               int* __restrict__ rowptr,
                                               int* __restrict__ deg,
                                               int* __restrict__ csr) {
    __shared__ int degL[NPB];
    __shared__ int curL[NPB];
    __shared__ int s[256];
    const int t = threadIdx.x, b = blockIdx.x;
    const int n0 = b << 10;
    const int nn = min(NPB, GN - n0);
    const int s0 = base_g[b], s1 = base_g[b + 1];
#pragma unroll
    for (int i = 0; i < 4; ++i) degL[t * 4 + i] = 0;
    __syncthreads();
    for (int i = s0 + t; i < s1; i += 256)
        atomicAdd(&degL[tmp[i] >> 18], 1);
    __syncthreads();
    int j0 = t * 4;
    int d0 = degL[j0], d1 = degL[j0 + 1], d2 = degL[j0 + 2], d3 = degL[j0 + 3];
    int tsum = d0 + d1 + d2 + d3;
    s[t] = tsum;
    for (int off = 1; off < 256; off <<= 1) {
        __syncthreads();
        int u = (t >= off) ? s[t - off] : 0;
        __syncthreads();
        s[t] += u;
    }
    __syncthreads();
    int excl = s[t] - tsum;
    int p0 = excl, p1 = p0 + d0, p2 = p1 + d1, p3 = p2 + d2;
    curL[j0] = p0; curL[j0 + 1] = p1; curL[j0 + 2] = p2; curL[j0 + 3] = p3;
    if (j0     < nn) { rowptr[n0 + j0]     = s0 + p0; deg[n0 + j0]     = d0; }
    if (j0 + 1 < nn) { rowptr[n0 + j0 + 1] = s0 + p1; deg[n0 + j0 + 1] = d1; }
    if (j0 + 2 < nn) { rowptr[n0 + j0 + 2] = s0 + p2; deg[n0 + j0 + 2] = d2; }
    if (j0 + 3 < nn) { rowptr[n0 + j0 + 3] = s0 + p3; deg[n0 + j0 + 3] = d3; }
    __syncthreads();
    for (int i = s0 + t; i < s1; i += 256) {
        int e = tmp[i];
        int r = atomicAdd(&curL[e >> 18], 1);
        csr[s0 + r] = e & 0x3FFFF;
    }
}

// ------- prep: W1 (128x64 f32, k-major) -> W1^T hi/lo f16 [64][128] ---------
__global__ __launch_bounds__(256) void k_prepW(const float* __restrict__ W1,
                                               f16* __restrict__ WhT,
                                               f16* __restrict__ WlT) {
    int t = blockIdx.x * 256 + threadIdx.x;   // 8192 elements
    if (t >= 128 * 64) return;
    int k = t & 127;          // consecutive threads -> consecutive k (coalesced writes)
    int n = t >> 7;
    float w = W1[k * 64 + n];
    f16 h = (f16)w;
    WhT[n * 128 + k] = h;
    WlT[n * 128 + k] = (f16)(w - (float)h);
}

// --- GEMM1 via MFMA (split-fp16 for fp32 accuracy) + fused logits -----------
__global__ __launch_bounds__(256, 3) void k_gemm1(const float* __restrict__ x,
                                               const f16* __restrict__ WhT,
                                               const f16* __restrict__ WlT,
                                               const float* __restrict__ a_src,
                                               const float* __restrict__ a_dst,
                                               unsigned short* __restrict__ h1f,
                                               unsigned short* __restrict__ l1,
                                               float* __restrict__ ad1) {
    __shared__ uint4 Bls[2048];               // 32 KB: slot kc*64 + (col^(kc&3))
    const int t = threadIdx.x;
    const int lane = t & 63;
    const int wv = t >> 6;
    const int ln15 = lane & 15;
    const int q = lane >> 4;                  // quarter-wave: k-group
    const int rowBase = blockIdx.x * 128 + wv * 32;

    // ---- A loads: 2 Mtiles x 8 Ksteps x (4 consecutive fp32), held in regs ----
    const float4* x4 = (const float4*)x;
    float4 araw[2][8];
#pragma unroll
    for (int m = 0; m < 2; ++m) {
        int row = rowBase + m * 16 + ln15;
        row = row < GN ? row : GN - 1;        // clamp (pad rows compute garbage)
        const float4* xr = x4 + (size_t)row * 32 + q;
#pragma unroll
        for (int s = 0; s < 8; ++s)
            araw[m][s] = xr[s * 4];           // k = s*16 + q*4 .. +3
    }

    // ---- stage B into LDS (coalesced linear reads, swizzled writes) ----
    const uint2* WhT2 = (const uint2*)WhT;    // v-th 8B chunk = W col v>>5, k (v&31)*4
    const uint2* WlT2 = (const uint2*)WlT;
#pragma unroll
    for (int i = 0; i < 8; ++i) {
        int v = t + i * 256;                  // 0..2047
        int col = v >> 5, kc = v & 31;
        uint2 bh = WhT2[v];
        uint2 bl = WlT2[v];
        Bls[kc * 64 + (col ^ (kc & 3))] = make_uint4(bh.x, bh.y, bl.x, bl.y);
    }
    __syncthreads();

    f32x4 acc[2][4];
#pragma unroll
    for (int m = 0; m < 2; ++m)
#pragma unroll
        for (int nt = 0; nt < 4; ++nt)
            acc[m][nt] = (f32x4){0.f, 0.f, 0.f, 0.f};

#pragma unroll
    for (int s = 0; s < 8; ++s) {
        // B fragments: lane holds W1[k = s*16 + q*4 + j][col = nt*16 + ln15]
        f16x4 bh[4], bl[4];
#pragma unroll
        for (int nt = 0; nt < 4; ++nt) {
            uint4 b = Bls[(s * 4 + q) * 64 + ((nt * 16 + ln15) ^ q)];
            bh[nt] = u2h4(make_uint2(b.x, b.y));
            bl[nt] = u2h4(make_uint2(b.z, b.w));
        }
#pragma unroll
        for (int m = 0; m < 2; ++m) {
            float4 r = araw[m][s];
            f16 h0 = (f16)r.x, h1 = (f16)r.y, h2 = (f16)r.z, h3 = (f16)r.w;
            f16x4 ah = {h0, h1, h2, h3};
            f16x4 al = {(f16)(r.x - (float)h0), (f16)(r.y - (float)h1),
                        (f16)(r.z - (float)h2), (f16)(r.w - (float)h3)};
#pragma unroll
            for (int nt = 0; nt < 4; ++nt) {
                acc[m][nt] = __builtin_amdgcn_mfma_f32_16x16x16f16(ah, bh[nt], acc[m][nt], 0, 0, 0);
                acc[m][nt] = __builtin_amdgcn_mfma_f32_16x16x16f16(al, bh[nt], acc[m][nt], 0, 0, 0);
                acc[m][nt] = __builtin_amdgcn_mfma_f32_16x16x16f16(ah, bl[nt], acc[m][nt], 0, 0, 0);
            }
        }
    }

    // ---- epilogue: C[row][col], col = nt*16 + ln15, row = base + q*4 + i ----
    float aSv[4], aDv[4];
#pragma unroll
    for (int nt = 0; nt < 4; ++nt) {
        aSv[nt] = a_src[nt * 16 + ln15];
        aDv[nt] = a_dst[nt * 16 + ln15];
    }
#pragma unroll
    for (int m = 0; m < 2; ++m) {
#pragma unroll
        for (int i = 0; i < 4; ++i) {
            int row = rowBase + m * 16 + q * 4 + i;
            bool ok = row < GN;
#pragma unroll
            for (int nt = 0; nt < 4; ++nt) {
                float v = acc[m][nt][i];
                if (ok) h1f[(size_t)row * 64 + nt * 16 + ln15] = f2h(v);
                float ps = v * aSv[nt];
                float pd = v * aDv[nt];
                ps += __shfl_xor(ps, 1); ps += __shfl_xor(ps, 2); ps += __shfl_xor(ps, 4);
                pd += __shfl_xor(pd, 1); pd += __shfl_xor(pd, 2); pd += __shfl_xor(pd, 4);
                if (ok && (ln15 & 7) == 0) {
                    int head = nt * 2 + (ln15 >> 3);
                    l1[(size_t)row * 8 + head] = f2h(ps);
                    ad1[row * 8 + head] = pd;
                }
            }
        }
    }
}

// ------- layer-1 gather: 2 dsts/wave; adjacency in regs; unroll-2 ping-pong;
// all gathers use wave-uniform SGPR base + 32-bit byte voffset (saddr form).
__global__ __launch_bounds__(256) void k_layer1(const int* __restrict__ rowptr,
                                                const int* __restrict__ deg,
                                                const int* __restrict__ csr,
                                                const unsigned short* __restrict__ h1f,
                                                const unsigned short* __restrict__ l1,
                                                const float* __restrict__ ad1,
                                                unsigned short* __restrict__ out1h) {
    const int tt = threadIdx.x & 63;
    const int h  = tt & 7;            // head (8 channels each)
    const int es = (tt >> 3) & 3;     // edge slot within dst
    const int hb = tt & 32;           // base lane of this half
    const int d  = blockIdx.x * 8 + (threadIdx.x >> 5);   // dst node (2 per wave)

    const int start = rowptr[d];
    const int dg    = deg[d];
    const float ad  = ad1[d * 8 + h];

    const int q5 = tt & 31;
    const int sv = csr[start + min(q5, dg - 1)];          // adjacency row in regs

    const unsigned hoffL = (unsigned)(h << 1);            // byte off in l1 row (16B)
    const unsigned hoffH = (unsigned)(h << 4);            // byte off in h1f row (128B)
    const char* l1b = (const char*)l1;
    const char* h1b = (const char*)h1f;

    float a0 = 0.f, a1 = 0.f, a2 = 0.f, a3 = 0.f;
    float a4 = 0.f, a5 = 0.f, a6 = 0.f, a7 = 0.f;
    float den = 0.f;

    const int limit = min(dg, 32);
    const int nit = (limit + 3) >> 2;                     // >= 1 (self-loops)
    union C { uint4 u; f16 hh[8]; };

    bool vA, vB;
    unsigned short lA, lB;
    C cA, cB;

    auto LD = [&](int j, bool& v, unsigned short& lv, C& c) {
        v = j < limit;
        int s = __shfl(sv, hb + (v ? j : 0));
        unsigned u = (unsigned)s;
        lv = *(const unsigned short*)(l1b + ((u << 4) + hoffL));
        c.u = *(const uint4*)(h1b + ((u << 7) + hoffH));
    };
    auto PROC = [&](bool v, unsigned short lv, const C& c) {
        float e = h2f(lv) + ad;
        e = fmaxf(e, SLOPE * e);
        float w = v ? __expf(e) : 0.f;
        den += w;
        a0 += w * (float)c.hh[0];
        a1 += w * (float)c.hh[1];
        a2 += w * (float)c.hh[2];
        a3 += w * (float)c.hh[3];
        a4 += w * (float)c.hh[4];
        a5 += w * (float)c.hh[5];
        a6 += w * (float)c.hh[6];
        a7 += w * (float)c.hh[7];
    };

    LD(es, vA, lA, cA);
    for (int k = 1; k < nit; k += 2) {
        LD(k * 4 + es, vB, lB, cB);
        PROC(vA, lA, cA);
        LD((k + 1) * 4 + es, vA, lA, cA);   // k+1 may be >= nit: val=false, harmless
        PROC(vB, lB, cB);
    }
    PROC(vA, lA, cA);

    // rare tail: deg > 32 (direct csr reads)
    for (int j = 32 + es; j < dg; j += 4) {
        int s3 = csr[start + j];
        unsigned u = (unsigned)s3;
        unsigned short lv = *(const unsigned short*)(l1b + ((u << 4) + hoffL));
        float e = h2f(lv) + ad;
        e = fmaxf(e, SLOPE * e);
        float w = __expf(e);
        den += w;
        C c3; c3.u = *(const uint4*)(h1b + ((u << 7) + hoffH));
        a0 += w * (float)c3.hh[0];
        a1 += w * (float)c3.hh[1];
        a2 += w * (float)c3.hh[2];
        a3 += w * (float)c3.hh[3];
        a4 += w * (float)c3.hh[4];
        a5 += w * (float)c3.hh[5];
        a6 += w * (float)c3.hh[6];
        a7 += w * (float)c3.hh[7];
    }

    a0 += __shfl_xor(a0, 8);  a0 += __shfl_xor(a0, 16);
    a1 += __shfl_xor(a1, 8);  a1 += __shfl_xor(a1, 16);
    a2 += __shfl_xor(a2, 8);  a2 += __shfl_xor(a2, 16);
    a3 += __shfl_xor(a3, 8);  a3 += __shfl_xor(a3, 16);
    a4 += __shfl_xor(a4, 8);  a4 += __shfl_xor(a4, 16);
    a5 += __shfl_xor(a5, 8);  a5 += __shfl_xor(a5, 16);
    a6 += __shfl_xor(a6, 8);  a6 += __shfl_xor(a6, 16);
    a7 += __shfl_xor(a7, 8);  a7 += __shfl_xor(a7, 16);
    den += __shfl_xor(den, 8); den += __shfl_xor(den, 16);

    if (es == 0) {
        float inv = 1.f / (den + 1e-16f);
        unsigned int p0 = (unsigned int)f2h(a0 * inv) | ((unsigned int)f2h(a1 * inv) << 16);
        unsigned int p1 = (unsigned int)f2h(a2 * inv) | ((unsigned int)f2h(a3 * inv) << 16);
        unsigned int p2 = (unsigned int)f2h(a4 * inv) | ((unsigned int)f2h(a5 * inv) << 16);
        unsigned int p3 = (unsigned int)f2h(a6 * inv) | ((unsigned int)f2h(a7 * inv) << 16);
        *(uint4*)(out1h + (size_t)d * 64 + h * 8) = make_uint4(p0, p1, p2, p3);
    }
}

// --- GEMM2 + fused logits: h2r[GN][20] fp16 (16 ch + logit in one 40B row) --
__global__ __launch_bounds__(256) void k_gemm2(const unsigned short* __restrict__ agg1,
                                               const float* __restrict__ b1,
                                               const float* __restrict__ W2,
                                               const float* __restrict__ a_src,
                                               const float* __restrict__ a_dst,
                                               unsigned short* __restrict__ h2r,
                                               float* __restrict__ ad2) {
    __shared__ float As[64][65];
    __shared__ float Bs[64][20];
    __shared__ float aS[16], aD[16];
    const int t = threadIdx.x;
    const int rowBase = blockIdx.x * 64;

    {
        int k = t >> 2, c = (t & 3) << 2;
        float4 w = ((const float4*)W2)[t];
        Bs[k][c] = w.x; Bs[k][c + 1] = w.y; Bs[k][c + 2] = w.z; Bs[k][c + 3] = w.w;
    }
    if (t < 16) { aS[t] = a_src[t]; aD[t] = a_dst[t]; }
    const ushort4* a4p = (const ushort4*)agg1;
    const float4* b14 = (const float4*)b1;
#pragma unroll
    for (int i = 0; i < 4; ++i) {
        int v = t + i * 256;
        int r = v >> 4;
        int kq = v & 15;
        int row = rowBase + r;
        float ax = 0.f, ay = 0.f, az = 0.f, aw = 0.f;
        if (row < GN) {
            ushort4 a = a4p[row * 16 + kq];
            float4 bb = b14[kq];
            ax = fmaxf(h2f(a.x) + bb.x, 0.f);
            ay = fmaxf(h2f(a.y) + bb.y, 0.f);
            az = fmaxf(h2f(a.z) + bb.z, 0.f);
            aw = fmaxf(h2f(a.w) + bb.w, 0.f);
        }
        int kk = kq << 2;
        As[kk][r] = ax; As[kk + 1][r] = ay; As[kk + 2][r] = az; As[kk + 3][r] = aw;
    }
    __syncthreads();
    const int r = t >> 2;
    const int cg = (t & 3) << 2;
    float acc0 = 0.f, acc1 = 0.f, acc2 = 0.f, acc3 = 0.f;
#pragma unroll 8
    for (int k = 0; k < 64; ++k) {
        float a = As[k][r];
        float4 b = *(const float4*)&Bs[k][cg];
        acc0 += a * b.x; acc1 += a * b.y; acc2 += a * b.z; acc3 += a * b.w;
    }
    float as_p = acc0 * aS[cg] + acc1 * aS[cg + 1] + acc2 * aS[cg + 2] + acc3 * aS[cg + 3];
    float ad_p = acc0 * aD[cg] + acc1 * aD[cg + 1] + acc2 * aD[cg + 2] + acc3 * aD[cg + 3];
    as_p += __shfl_xor(as_p, 1); as_p += __shfl_xor(as_p, 2);
    ad_p += __shfl_xor(ad_p, 1); ad_p += __shfl_xor(ad_p, 2);
    int row = rowBase + r;
    if (row < GN) {
        ushort4 fv = make_ushort4(f2h(acc0), f2h(acc1), f2h(acc2), f2h(acc3));
        *(ushort4*)(h2r + (size_t)row * 20 + cg) = fv;   // row*40B + cg*2 is 8B-aligned
        if ((t & 3) == 0) {
            h2r[(size_t)row * 20 + 16] = f2h(as_p);
            ad2[row] = ad_p;
        }
    }
}

// ------- layer-2 gather: one wave/dst, 8 edge-slots x 8 ch-pairs ------------
// 32-bit byte offsets (saddr form): logit at off+32 (imm), pair at off+p*4.
__global__ __launch_bounds__(256) void k_layer2(const int* __restrict__ rowptr,
                                                const int* __restrict__ deg,
                                                const int* __restrict__ csr,
                                                const unsigned short* __restrict__ h2r,
                                                const float* __restrict__ ad2,
                                                float* __restrict__ out2) {
    int d = __builtin_amdgcn_readfirstlane(blockIdx.x * 4 + (threadIdx.x >> 6));
    int tt = threadIdx.x & 63;
    int p = tt & 7;                   // channel pair (ch 2p, 2p+1)
    int sub = tt >> 3;                // 8 edge slots
    int start = rowptr[d];
    int dg = deg[d];
    float ad = ad2[d];
    int sv = csr[start + min(tt, dg - 1)];   // whole adjacency in registers
    int full = min(dg, 64);
    const char* h2b = (const char*)h2r;
    const unsigned poff = (unsigned)(p << 2);
    float den = 0.f, accx = 0.f, accy = 0.f;
    for (int base = 0; base < full; base += 8) {
        int j = base + sub;
        bool val = j < full;
        int s = __shfl(sv, j < 64 ? j : 0);
        unsigned off = (unsigned)s * 40u;
        float w = val ? __expf(lrelu(h2f(*(const unsigned short*)(h2b + off + 32)) + ad)) : 0.f;
        unsigned int gp = *(const unsigned int*)(h2b + off + poff);
        den += w;
        accx += w * h2f((unsigned short)(gp & 0xffff));
        accy += w * h2f((unsigned short)(gp >> 16));
    }
    // tail for deg > 64 (essentially never)
    for (int base = 64; base < dg; base += 8) {
        int j = base + sub;
        bool val = j < dg;
        int s = csr[start + (val ? j : 0)];
        unsigned off = (unsigned)s * 40u;
        float w = val ? __expf(lrelu(h2f(*(const unsigned short*)(h2b + off + 32)) + ad)) : 0.f;
        unsigned int gp = *(const unsigned int*)(h2b + off + poff);
        den += w;
        accx += w * h2f((unsigned short)(gp & 0xffff));
        accy += w * h2f((unsigned short)(gp >> 16));
    }
    accx += __shfl_xor(accx, 8); accx += __shfl_xor(accx, 16); accx += __shfl_xor(accx, 32);
    accy += __shfl_xor(accy, 8); accy += __shfl_xor(accy, 16); accy += __shfl_xor(accy, 32);
    den  += __shfl_xor(den, 8);  den  += __shfl_xor(den, 16);  den  += __shfl_xor(den, 32);
    if (sub == 0) {
        float inv = 1.f / (den + 1e-16f);
        ((float2*)out2)[(size_t)d * 8 + p] = make_float2(accx * inv, accy * inv);
    }
}

// -------- final: out[n,2] = concat_g(out2[g,n,:]+b2) @ Wf + bf --------------
__global__ __launch_bounds__(256) void k_final(const float* __restrict__ agg2,
                                               const float* __restrict__ b2,
                                               const float* __restrict__ Wf,
                                               const float* __restrict__ bf,
                                               float* __restrict__ out) {
    int n = blockIdx.x * 256 + threadIdx.x;
    if (n >= N_NODES) return;
    float o0 = bf[0], o1 = bf[1];
#pragma unroll
    for (int g = 0; g < G; ++g) {
        const float4* v4 = (const float4*)agg2 + (size_t)(g * N_NODES + n) * 4;
#pragma unroll
        for (int q = 0; q < 4; ++q) {
            float4 v = v4[q];
            float4 b = ((const float4*)b2)[q];
            v.x += b.x; v.y += b.y; v.z += b.z; v.w += b.w;
            int kb = g * 16 + q * 4;
            o0 += v.x * Wf[(kb + 0) * 2]     + v.y * Wf[(kb + 1) * 2]
                + v.z * Wf[(kb + 2) * 2]     + v.w * Wf[(kb + 3) * 2];
            o1 += v.x * Wf[(kb + 0) * 2 + 1] + v.y * Wf[(kb + 1) * 2 + 1]
                + v.z * Wf[(kb + 2) * 2 + 1] + v.w * Wf[(kb + 3) * 2 + 1];
        }
    }
    out[n * 2]     = o0;
    out[n * 2 + 1] = o1;
}

extern "C" void kernel_launch(void* const* d_in, const int* in_sizes, int n_in,
                              void* d_out, int out_size, void* d_ws, size_t ws_size,
                              hipStream_t stream) {
    const float* x      = (const float*)d_in[0];
    const int*   ei     = (const int*)d_in[1];
    const float* W1     = (const float*)d_in[2];
    const float* a_src1 = (const float*)d_in[3];
    const float* a_dst1 = (const float*)d_in[4];
    const float* b1     = (const float*)d_in[5];
    const float* W2     = (const float*)d_in[6];
    const float* a_src2 = (const float*)d_in[7];
    const float* a_dst2 = (const float*)d_in[8];
    const float* b2     = (const float*)d_in[9];
    const float* Wf     = (const float*)d_in[10];
    const float* bf     = (const float*)d_in[11];
    float* out = (float*)d_out;

    // workspace layout (lifetime aliasing):
    //   region A (36 MB): h1f[GN*64 u16] + l1[GN*8 u16]   (gemm1 -> layer1)
    //                     -> h2r[GN*20 u16] + out2[GN*16 f32]
    //   region B (32 MB): out1h[GN*64 u16]                (layer1 -> gemm2)
    //   region C (8 MB):  ad1[GN*8 f32] -> ad2[GN f32]
    //   ints: rowptr, deg, base_g, T, H, tmp, csr
    //   tail: W1^T hi/lo fp16 (32 KB)
    unsigned short* h1f = (unsigned short*)d_ws;             // GN*64 u16 (128B rows)
    unsigned short* l1  = h1f + (size_t)GN * 64;             // GN*8 u16
    unsigned short* h2r = h1f;                               // GN*20 u16 (alias)
    float* out2 = (float*)(h2r + (size_t)GN * 20);           // GN*16 f32 (alias; 8B-aligned)
    unsigned short* out1h = h1f + (size_t)GN * 72;           // GN*64 u16
    float* ad1  = (float*)(out1h + (size_t)GN * 64);         // GN*8 f32
    float* ad2  = ad1;                                       // GN (alias)
    int*   iws    = (int*)(ad1 + (size_t)GN * 8);
    int*   rowptr = iws;                                     // GN
    int*   deg    = rowptr + GN;                             // GN
    int*   base_g = deg + GN;                                // NBUK+1
    int*   T      = base_g + (NBUK + 1);                     // NBUK
    int*   H      = T + NBUK;                                // NBLK_E*NBUK
    int*   tmp    = H + (size_t)NBLK_E * NBUK;               // GE
    int*   csr    = tmp + GE;                                // GE
    uintptr_t wp = ((uintptr_t)(csr + GE) + 15) & ~(uintptr_t)15;
    f16* WhT = (f16*)wp;                                     // 64*128 f16
    f16* WlT = WhT + 64 * 128;                               // 64*128 f16

    // CSR build via bucket sort (no global atomics, coalesced writes)
    k_hist   <<<NBLK_E, 256, 0, stream>>>(ei, H);
    k_scanH  <<<NBUK,   256, 0, stream>>>(H, T);
    k_scanT  <<<1,      256, 0, stream>>>(T, base_g);
    k_scatter<<<NBLK_E, 256, 0, stream>>>(ei, H, base_g, tmp);
    k_build  <<<NBUK,   256, 0, stream>>>(base_g, tmp, rowptr, deg, csr);

    k_prepW  <<<32, 256, 0, stream>>>(W1, WhT, WlT);
    k_gemm1  <<<(GN + 127) / 128, 256, 0, stream>>>(x, WhT, WlT, a_src1, a_dst1, h1f, l1, ad1);
    k_layer1 <<<GN / 8, 256, 0, stream>>>(rowptr, deg, csr, h1f, l1, ad1, out1h);
    k_gemm2  <<<(GN + 63) / 64, 256, 0, stream>>>(out1h, b1, W2, a_src2, a_dst2, h2r, ad2);
    k_layer2 <<<GN / 4, 256, 0, stream>>>(rowptr, deg, csr, h2r, ad2, out2);
    k_final  <<<(N_NODES + 255) / 256, 256, 0, stream>>>(out2, b2, Wf, bf, out);
}

// Round 7
// 498.187 us; speedup vs baseline: 1.1745x; 1.0420x over previous
//
#include <hip/hip_runtime.h>

// Problem constants (fixed by the reference setup)
constexpr int N_NODES = 50000;
constexpr int G = 5;
constexpr int E = 850000;            // E0 (800000) + N self-loops
constexpr int GN = G * N_NODES;      // 250000
constexpr int GE = G * E;            // 4,250,000
constexpr float SLOPE = 0.2f;

// Bucket sort parameters
constexpr int NPB = 1024;                        // nodes per bucket
constexpr int NBUK = (GN + NPB - 1) / NPB;       // 245
constexpr int EPB = 4096;                        // edges per block (256 thr x 16)
constexpr int NBLK_E = (GE + EPB - 1) / EPB;     // 1038

typedef _Float16 f16;
typedef f16 f16x4 __attribute__((ext_vector_type(4)));
typedef float f32x4 __attribute__((ext_vector_type(4)));

static __device__ __forceinline__ float lrelu(float e) {
    return e > 0.f ? e : SLOPE * e;
}
static __device__ __forceinline__ unsigned short f2h(float f) {
    union { _Float16 h; unsigned short u; } v;
    v.h = (_Float16)f;
    return v.u;
}
static __device__ __forceinline__ float h2f(unsigned short u) {
    union { unsigned short u; _Float16 h; } v;
    v.u = u;
    return (float)v.h;
}
static __device__ __forceinline__ f16x4 u2h4(uint2 u) {
    union { uint2 u; f16x4 h; } c;
    c.u = u;
    return c.h;
}

// ---------------- pass A1: per-block bucket histogram -----------------------
__global__ __launch_bounds__(256) void k_hist(const int* __restrict__ ei,
                                              int* __restrict__ H) {
    __shared__ int hist[NBUK];
    const int t = threadIdx.x, bi = blockIdx.x;
    for (int j = t; j < NBUK; j += 256) hist[j] = 0;
    __syncthreads();
#pragma unroll
    for (int i = 0; i < 16; ++i) {
        int idx = bi * EPB + i * 256 + t;
        if (idx < GE) {
            int g = idx / E;
            int el = idx - g * E;
            int dst = ei[(size_t)g * 2 * E + E + el];
            atomicAdd(&hist[(g * N_NODES + dst) >> 10], 1);
        }
    }
    __syncthreads();
    for (int j = t; j < NBUK; j += 256) H[(size_t)bi * NBUK + j] = hist[j];
}

// ------- pass A2a: per bucket, exclusive scan of H over blocks; totals ------
__global__ __launch_bounds__(256) void k_scanH(int* __restrict__ H,
                                               int* __restrict__ T) {
    __shared__ int s[256];
    const int t = threadIdx.x, b = blockIdx.x;
    int run = 0;
    for (int c = 0; c < NBLK_E; c += 256) {
        int bi = c + t;
        int v = (bi < NBLK_E) ? H[(size_t)bi * NBUK + b] : 0;
        s[t] = v;
        for (int off = 1; off < 256; off <<= 1) {
            __syncthreads();
            int u = (t >= off) ? s[t - off] : 0;
            __syncthreads();
            s[t] += u;
        }
        __syncthreads();
        int excl = s[t] - v;
        if (bi < NBLK_E) H[(size_t)bi * NBUK + b] = run + excl;
        run += s[255];
        __syncthreads();
    }
    if (t == 0) T[b] = run;
}

// ------- pass A2b: exclusive scan of bucket totals -> bucket bases ----------
__global__ __launch_bounds__(256) void k_scanT(const int* __restrict__ T,
                                               int* __restrict__ base_g) {
    __shared__ int s[256];
    const int t = threadIdx.x;
    int v = (t < NBUK) ? T[t] : 0;
    s[t] = v;
    for (int off = 1; off < 256; off <<= 1) {
        __syncthreads();
        int u = (t >= off) ? s[t - off] : 0;
        __syncthreads();
        s[t] += u;
    }
    __syncthreads();
    if (t < NBUK) base_g[t] = s[t] - v;
    if (t == 0) base_g[NBUK] = s[255];
}

// ------- pass A3: scatter packed (dstLow10<<18 | src) into bucket groups ----
__global__ __launch_bounds__(256) void k_scatter(const int* __restrict__ ei,
                                                 const int* __restrict__ H,
                                                 const int* __restrict__ base_g,
                                                 int* __restrict__ tmp) {
    __shared__ int cnt[NBUK];
    __shared__ int off[NBUK];
    const int t = threadIdx.x, bi = blockIdx.x;
    for (int j = t; j < NBUK; j += 256) {
        cnt[j] = 0;
        off[j] = base_g[j] + H[(size_t)bi * NBUK + j];
    }
    __syncthreads();
#pragma unroll
    for (int i = 0; i < 16; ++i) {
        int idx = bi * EPB + i * 256 + t;
        if (idx < GE) {
            int g = idx / E;
            int el = idx - g * E;
            const int* eb = ei + (size_t)g * 2 * E;
            int src = eb[el];
            int dst = eb[E + el];
            int gdst = g * N_NODES + dst;
            int b = gdst >> 10;
            int rank = atomicAdd(&cnt[b], 1);
            tmp[off[b] + rank] = ((gdst & 1023) << 18) | (g * N_NODES + src);
        }
    }
}

// ------- pass B: per-bucket LDS counting sort -> rowptr/deg/csr -------------
__global__ __launch_bounds__(256) void k_build(const int* __restrict__ base_g,
                                               const int* __restrict__ tmp,
                                               int* __restrict__ rowptr,
                                               int* __restrict__ deg,
                                               int* __restrict__ csr) {
    __shared__ int degL[NPB];
    __shared__ int curL[NPB];
    __shared__ int s[256];
    const int t = threadIdx.x, b = blockIdx.x;
    const int n0 = b << 10;
    const int nn = min(NPB, GN - n0);
    const int s0 = base_g[b], s1 = base_g[b + 1];
#pragma unroll
    for (int i = 0; i < 4; ++i) degL[t * 4 + i] = 0;
    __syncthreads();
    for (int i = s0 + t; i < s1; i += 256)
        atomicAdd(&degL[tmp[i] >> 18], 1);
    __syncthreads();
    int j0 = t * 4;
    int d0 = degL[j0], d1 = degL[j0 + 1], d2 = degL[j0 + 2], d3 = degL[j0 + 3];
    int tsum = d0 + d1 + d2 + d3;
    s[t] = tsum;
    for (int off = 1; off < 256; off <<= 1) {
        __syncthreads();
        int u = (t >= off) ? s[t - off] : 0;
        __syncthreads();
        s[t] += u;
    }
    __syncthreads();
    int excl = s[t] - tsum;
    int p0 = excl, p1 = p0 + d0, p2 = p1 + d1, p3 = p2 + d2;
    curL[j0] = p0; curL[j0 + 1] = p1; curL[j0 + 2] = p2; curL[j0 + 3] = p3;
    if (j0     < nn) { rowptr[n0 + j0]     = s0 + p0; deg[n0 + j0]     = d0; }
    if (j0 + 1 < nn) { rowptr[n0 + j0 + 1] = s0 + p1; deg[n0 + j0 + 1] = d1; }
    if (j0 + 2 < nn) { rowptr[n0 + j0 + 2] = s0 + p2; deg[n0 + j0 + 2] = d2; }
    if (j0 + 3 < nn) { rowptr[n0 + j0 + 3] = s0 + p3; deg[n0 + j0 + 3] = d3; }
    __syncthreads();
    for (int i = s0 + t; i < s1; i += 256) {
        int e = tmp[i];
        int r = atomicAdd(&curL[e >> 18], 1);
        csr[s0 + r] = e & 0x3FFFF;
    }
}

// ------- prep: W1 (128x64 f32, k-major) -> W1^T hi/lo f16 [64][128] ---------
__global__ __launch_bounds__(256) void k_prepW(const float* __restrict__ W1,
                                               f16* __restrict__ WhT,
                                               f16* __restrict__ WlT) {
    int t = blockIdx.x * 256 + threadIdx.x;   // 8192 elements
    if (t >= 128 * 64) return;
    int k = t & 127;          // consecutive threads -> consecutive k (coalesced writes)
    int n = t >> 7;
    float w = W1[k * 64 + n];
    f16 h = (f16)w;
    WhT[n * 128 + k] = h;
    WlT[n * 128 + k] = (f16)(w - (float)h);
}

// --- GEMM1 via MFMA (split-fp16 for fp32 accuracy) + fused logits -----------
__global__ __launch_bounds__(256, 3) void k_gemm1(const float* __restrict__ x,
                                               const f16* __restrict__ WhT,
                                               const f16* __restrict__ WlT,
                                               const float* __restrict__ a_src,
                                               const float* __restrict__ a_dst,
                                               unsigned short* __restrict__ h1f,
                                               unsigned short* __restrict__ l1,
                                               float* __restrict__ ad1) {
    __shared__ uint4 Bls[2048];               // 32 KB: slot kc*64 + (col^(kc&3))
    const int t = threadIdx.x;
    const int lane = t & 63;
    const int wv = t >> 6;
    const int ln15 = lane & 15;
    const int q = lane >> 4;                  // quarter-wave: k-group
    const int rowBase = blockIdx.x * 128 + wv * 32;

    // ---- A loads: 2 Mtiles x 8 Ksteps x (4 consecutive fp32), held in regs ----
    const float4* x4 = (const float4*)x;
    float4 araw[2][8];
#pragma unroll
    for (int m = 0; m < 2; ++m) {
        int row = rowBase + m * 16 + ln15;
        row = row < GN ? row : GN - 1;        // clamp (pad rows compute garbage)
        const float4* xr = x4 + (size_t)row * 32 + q;
#pragma unroll
        for (int s = 0; s < 8; ++s)
            araw[m][s] = xr[s * 4];           // k = s*16 + q*4 .. +3
    }

    // ---- stage B into LDS (coalesced linear reads, swizzled writes) ----
    const uint2* WhT2 = (const uint2*)WhT;    // v-th 8B chunk = W col v>>5, k (v&31)*4
    const uint2* WlT2 = (const uint2*)WlT;
#pragma unroll
    for (int i = 0; i < 8; ++i) {
        int v = t + i * 256;                  // 0..2047
        int col = v >> 5, kc = v & 31;
        uint2 bh = WhT2[v];
        uint2 bl = WlT2[v];
        Bls[kc * 64 + (col ^ (kc & 3))] = make_uint4(bh.x, bh.y, bl.x, bl.y);
    }
    __syncthreads();

    f32x4 acc[2][4];
#pragma unroll
    for (int m = 0; m < 2; ++m)
#pragma unroll
        for (int nt = 0; nt < 4; ++nt)
            acc[m][nt] = (f32x4){0.f, 0.f, 0.f, 0.f};

#pragma unroll
    for (int s = 0; s < 8; ++s) {
        // B fragments: lane holds W1[k = s*16 + q*4 + j][col = nt*16 + ln15]
        f16x4 bh[4], bl[4];
#pragma unroll
        for (int nt = 0; nt < 4; ++nt) {
            uint4 b = Bls[(s * 4 + q) * 64 + ((nt * 16 + ln15) ^ q)];
            bh[nt] = u2h4(make_uint2(b.x, b.y));
            bl[nt] = u2h4(make_uint2(b.z, b.w));
        }
#pragma unroll
        for (int m = 0; m < 2; ++m) {
            float4 r = araw[m][s];
            f16 h0 = (f16)r.x, h1 = (f16)r.y, h2 = (f16)r.z, h3 = (f16)r.w;
            f16x4 ah = {h0, h1, h2, h3};
            f16x4 al = {(f16)(r.x - (float)h0), (f16)(r.y - (float)h1),
                        (f16)(r.z - (float)h2), (f16)(r.w - (float)h3)};
#pragma unroll
            for (int nt = 0; nt < 4; ++nt) {
                acc[m][nt] = __builtin_amdgcn_mfma_f32_16x16x16f16(ah, bh[nt], acc[m][nt], 0, 0, 0);
                acc[m][nt] = __builtin_amdgcn_mfma_f32_16x16x16f16(al, bh[nt], acc[m][nt], 0, 0, 0);
                acc[m][nt] = __builtin_amdgcn_mfma_f32_16x16x16f16(ah, bl[nt], acc[m][nt], 0, 0, 0);
            }
        }
    }

    // ---- epilogue: C[row][col], col = nt*16 + ln15, row = base + q*4 + i ----
    float aSv[4], aDv[4];
#pragma unroll
    for (int nt = 0; nt < 4; ++nt) {
        aSv[nt] = a_src[nt * 16 + ln15];
        aDv[nt] = a_dst[nt * 16 + ln15];
    }
#pragma unroll
    for (int m = 0; m < 2; ++m) {
#pragma unroll
        for (int i = 0; i < 4; ++i) {
            int row = rowBase + m * 16 + q * 4 + i;
            bool ok = row < GN;
#pragma unroll
            for (int nt = 0; nt < 4; ++nt) {
                float v = acc[m][nt][i];
                if (ok) h1f[(size_t)row * 64 + nt * 16 + ln15] = f2h(v);
                float ps = v * aSv[nt];
                float pd = v * aDv[nt];
                ps += __shfl_xor(ps, 1); ps += __shfl_xor(ps, 2); ps += __shfl_xor(ps, 4);
                pd += __shfl_xor(pd, 1); pd += __shfl_xor(pd, 2); pd += __shfl_xor(pd, 4);
                if (ok && (ln15 & 7) == 0) {
                    int head = nt * 2 + (ln15 >> 3);
                    l1[(size_t)row * 8 + head] = f2h(ps);
                    ad1[row * 8 + head] = pd;
                }
            }
        }
    }
}

// ------- layer-1 gather: 2 dsts/wave; adjacency in regs; unroll-2 ping-pong;
// all gathers use wave-uniform SGPR base + 32-bit byte voffset (saddr form).
__global__ __launch_bounds__(256) void k_layer1(const int* __restrict__ rowptr,
                                                const int* __restrict__ deg,
                                                const int* __restrict__ csr,
                                                const unsigned short* __restrict__ h1f,
                                                const unsigned short* __restrict__ l1,
                                                const float* __restrict__ ad1,
                                                unsigned short* __restrict__ out1h) {
    const int tt = threadIdx.x & 63;
    const int h  = tt & 7;            // head (8 channels each)
    const int es = (tt >> 3) & 3;     // edge slot within dst
    const int hb = tt & 32;           // base lane of this half
    const int d  = blockIdx.x * 8 + (threadIdx.x >> 5);   // dst node (2 per wave)

    const int start = rowptr[d];
    const int dg    = deg[d];
    const float ad  = ad1[d * 8 + h];

    const int q5 = tt & 31;
    const int sv = csr[start + min(q5, dg - 1)];          // adjacency row in regs

    const unsigned hoffL = (unsigned)(h << 1);            // byte off in l1 row (16B)
    const unsigned hoffH = (unsigned)(h << 4);            // byte off in h1f row (128B)
    const char* l1b = (const char*)l1;
    const char* h1b = (const char*)h1f;

    float a0 = 0.f, a1 = 0.f, a2 = 0.f, a3 = 0.f;
    float a4 = 0.f, a5 = 0.f, a6 = 0.f, a7 = 0.f;
    float den = 0.f;

    const int limit = min(dg, 32);
    const int nit = (limit + 3) >> 2;                     // >= 1 (self-loops)
    union C { uint4 u; f16 hh[8]; };

    bool vA, vB;
    unsigned short lA, lB;
    C cA, cB;

    auto LD = [&](int j, bool& v, unsigned short& lv, C& c) {
        v = j < limit;
        int s = __shfl(sv, hb + (v ? j : 0));
        unsigned u = (unsigned)s;
        lv = *(const unsigned short*)(l1b + ((u << 4) + hoffL));
        c.u = *(const uint4*)(h1b + ((u << 7) + hoffH));
    };
    auto PROC = [&](bool v, unsigned short lv, const C& c) {
        float e = h2f(lv) + ad;
        e = fmaxf(e, SLOPE * e);
        float w = v ? __expf(e) : 0.f;
        den += w;
        a0 += w * (float)c.hh[0];
        a1 += w * (float)c.hh[1];
        a2 += w * (float)c.hh[2];
        a3 += w * (float)c.hh[3];
        a4 += w * (float)c.hh[4];
        a5 += w * (float)c.hh[5];
        a6 += w * (float)c.hh[6];
        a7 += w * (float)c.hh[7];
    };

    LD(es, vA, lA, cA);
    for (int k = 1; k < nit; k += 2) {
        LD(k * 4 + es, vB, lB, cB);
        PROC(vA, lA, cA);
        LD((k + 1) * 4 + es, vA, lA, cA);   // k+1 may be >= nit: val=false, harmless
        PROC(vB, lB, cB);
    }
    PROC(vA, lA, cA);

    // rare tail: deg > 32 (direct csr reads)
    for (int j = 32 + es; j < dg; j += 4) {
        int s3 = csr[start + j];
        unsigned u = (unsigned)s3;
        unsigned short lv = *(const unsigned short*)(l1b + ((u << 4) + hoffL));
        float e = h2f(lv) + ad;
        e = fmaxf(e, SLOPE * e);
        float w = __expf(e);
        den += w;
        C c3; c3.u = *(const uint4*)(h1b + ((u << 7) + hoffH));
        a0 += w * (float)c3.hh[0];
        a1 += w * (float)c3.hh[1];
        a2 += w * (float)c3.hh[2];
        a3 += w * (float)c3.hh[3];
        a4 += w * (float)c3.hh[4];
        a5 += w * (float)c3.hh[5];
        a6 += w * (float)c3.hh[6];
        a7 += w * (float)c3.hh[7];
    }

    a0 += __shfl_xor(a0, 8);  a0 += __shfl_xor(a0, 16);
    a1 += __shfl_xor(a1, 8);  a1 += __shfl_xor(a1, 16);
    a2 += __shfl_xor(a2, 8);  a2 += __shfl_xor(a2, 16);
    a3 += __shfl_xor(a3, 8);  a3 += __shfl_xor(a3, 16);
    a4 += __shfl_xor(a4, 8);  a4 += __shfl_xor(a4, 16);
    a5 += __shfl_xor(a5, 8);  a5 += __shfl_xor(a5, 16);
    a6 += __shfl_xor(a6, 8);  a6 += __shfl_xor(a6, 16);
    a7 += __shfl_xor(a7, 8);  a7 += __shfl_xor(a7, 16);
    den += __shfl_xor(den, 8); den += __shfl_xor(den, 16);

    if (es == 0) {
        float inv = 1.f / (den + 1e-16f);
        unsigned int p0 = (unsigned int)f2h(a0 * inv) | ((unsigned int)f2h(a1 * inv) << 16);
        unsigned int p1 = (unsigned int)f2h(a2 * inv) | ((unsigned int)f2h(a3 * inv) << 16);
        unsigned int p2 = (unsigned int)f2h(a4 * inv) | ((unsigned int)f2h(a5 * inv) << 16);
        unsigned int p3 = (unsigned int)f2h(a6 * inv) | ((unsigned int)f2h(a7 * inv) << 16);
        *(uint4*)(out1h + (size_t)d * 64 + h * 8) = make_uint4(p0, p1, p2, p3);
    }
}

// --- GEMM2 + fused logits: h2r[GN][20] fp16 (16 ch + logit in one 40B row) --
__global__ __launch_bounds__(256) void k_gemm2(const unsigned short* __restrict__ agg1,
                                               const float* __restrict__ b1,
                                               const float* __restrict__ W2,
                                               const float* __restrict__ a_src,
                                               const float* __restrict__ a_dst,
                                               unsigned short* __restrict__ h2r,
                                               float* __restrict__ ad2) {
    __shared__ float As[64][65];
    __shared__ float Bs[64][20];
    __shared__ float aS[16], aD[16];
    const int t = threadIdx.x;
    const int rowBase = blockIdx.x * 64;

    {
        int k = t >> 2, c = (t & 3) << 2;
        float4 w = ((const float4*)W2)[t];
        Bs[k][c] = w.x; Bs[k][c + 1] = w.y; Bs[k][c + 2] = w.z; Bs[k][c + 3] = w.w;
    }
    if (t < 16) { aS[t] = a_src[t]; aD[t] = a_dst[t]; }
    const ushort4* a4p = (const ushort4*)agg1;
    const float4* b14 = (const float4*)b1;
#pragma unroll
    for (int i = 0; i < 4; ++i) {
        int v = t + i * 256;
        int r = v >> 4;
        int kq = v & 15;
        int row = rowBase + r;
        float ax = 0.f, ay = 0.f, az = 0.f, aw = 0.f;
        if (row < GN) {
            ushort4 a = a4p[row * 16 + kq];
            float4 bb = b14[kq];
            ax = fmaxf(h2f(a.x) + bb.x, 0.f);
            ay = fmaxf(h2f(a.y) + bb.y, 0.f);
            az = fmaxf(h2f(a.z) + bb.z, 0.f);
            aw = fmaxf(h2f(a.w) + bb.w, 0.f);
        }
        int kk = kq << 2;
        As[kk][r] = ax; As[kk + 1][r] = ay; As[kk + 2][r] = az; As[kk + 3][r] = aw;
    }
    __syncthreads();
    const int r = t >> 2;
    const int cg = (t & 3) << 2;
    float acc0 = 0.f, acc1 = 0.f, acc2 = 0.f, acc3 = 0.f;
#pragma unroll 8
    for (int k = 0; k < 64; ++k) {
        float a = As[k][r];
        float4 b = *(const float4*)&Bs[k][cg];
        acc0 += a * b.x; acc1 += a * b.y; acc2 += a * b.z; acc3 += a * b.w;
    }
    float as_p = acc0 * aS[cg] + acc1 * aS[cg + 1] + acc2 * aS[cg + 2] + acc3 * aS[cg + 3];
    float ad_p = acc0 * aD[cg] + acc1 * aD[cg + 1] + acc2 * aD[cg + 2] + acc3 * aD[cg + 3];
    as_p += __shfl_xor(as_p, 1); as_p += __shfl_xor(as_p, 2);
    ad_p += __shfl_xor(ad_p, 1); ad_p += __shfl_xor(ad_p, 2);
    int row = rowBase + r;
    if (row < GN) {
        ushort4 fv = make_ushort4(f2h(acc0), f2h(acc1), f2h(acc2), f2h(acc3));
        *(ushort4*)(h2r + (size_t)row * 20 + cg) = fv;   // row*40B + cg*2 is 8B-aligned
        if ((t & 3) == 0) {
            h2r[(size_t)row * 20 + 16] = f2h(as_p);
            ad2[row] = ad_p;
        }
    }
}

// ------- layer-2 gather: one wave/dst; weights precomputed one-edge-per-lane,
// den via full-wave butterfly; inner loop = shfl+gather+2FMA, ping-ponged.
__global__ __launch_bounds__(256) void k_layer2(const int* __restrict__ rowptr,
                                                const int* __restrict__ deg,
                                                const int* __restrict__ csr,
                                                const unsigned short* __restrict__ h2r,
                                                const float* __restrict__ ad2,
                                                float* __restrict__ out2) {
    int d = __builtin_amdgcn_readfirstlane(blockIdx.x * 4 + (threadIdx.x >> 6));
    int tt = threadIdx.x & 63;
    int p = tt & 7;                   // channel pair (ch 2p, 2p+1)
    int sub = tt >> 3;                // 8 edge slots
    int start = rowptr[d];
    int dg = deg[d];
    float ad = ad2[d];
    int sv = csr[start + min(tt, dg - 1)];   // whole adjacency in registers
    const char* h2b = (const char*)h2r;

    // per-lane softmax weight for edge tt (one gather + one exp per edge)
    float wl;
    {
        float e = h2f(*(const unsigned short*)(h2b + ((unsigned)sv * 40u + 32u))) + ad;
        e = fmaxf(e, SLOPE * e);
        wl = (tt < dg) ? __expf(e) : 0.f;
    }
    // den = full-wave sum of wl (each edge counted once)
    float den = wl;
    den += __shfl_xor(den, 1);  den += __shfl_xor(den, 2);  den += __shfl_xor(den, 4);
    den += __shfl_xor(den, 8);  den += __shfl_xor(den, 16); den += __shfl_xor(den, 32);

    const unsigned poff = (unsigned)(p << 2);
    const int full = min(dg, 64);
    const int nit = (full + 7) >> 3;          // >= 1 (self-loops)
    float accx = 0.f, accy = 0.f;

    float wA, wB;
    unsigned gA, gB;
    auto LD2 = [&](int i, float& w, unsigned& gp) {
        int j = i * 8 + sub;
        int jc = j & 63;
        w = __shfl(wl, jc);
        if (j >= 64) w = 0.f;                 // prefetch past end of window
        int s = __shfl(sv, jc);
        gp = *(const unsigned*)(h2b + ((unsigned)s * 40u + poff));
    };
    auto PR2 = [&](float w, unsigned gp) {
        accx += w * h2f((unsigned short)(gp & 0xffff));
        accy += w * h2f((unsigned short)(gp >> 16));
    };

    LD2(0, wA, gA);
    for (int k = 1; k < nit; k += 2) {
        LD2(k, wB, gB);
        PR2(wA, gA);
        LD2(k + 1, wA, gA);                   // may over-read one slot: w forced 0
        PR2(wB, gB);
    }
    PR2(wA, gA);

    // tail for deg > 64 (essentially never): per-sub weight, den via sub-reduce
    if (dg > 64) {
        float denT = 0.f;
        for (int base = 64; base < dg; base += 8) {
            int j = base + sub;
            bool val = j < dg;
            int s = csr[start + (val ? j : 0)];
            unsigned off = (unsigned)s * 40u;
            float e = h2f(*(const unsigned short*)(h2b + off + 32u)) + ad;
            e = fmaxf(e, SLOPE * e);
            float w = val ? __expf(e) : 0.f;
            unsigned gp = *(const unsigned*)(h2b + off + poff);
            denT += w;
            accx += w * h2f((unsigned short)(gp & 0xffff));
            accy += w * h2f((unsigned short)(gp >> 16));
        }
        denT += __shfl_xor(denT, 8); denT += __shfl_xor(denT, 16); denT += __shfl_xor(denT, 32);
        den += denT;
    }

    accx += __shfl_xor(accx, 8); accx += __shfl_xor(accx, 16); accx += __shfl_xor(accx, 32);
    accy += __shfl_xor(accy, 8); accy += __shfl_xor(accy, 16); accy += __shfl_xor(accy, 32);
    if (sub == 0) {
        float inv = 1.f / (den + 1e-16f);
        ((float2*)out2)[(size_t)d * 8 + p] = make_float2(accx * inv, accy * inv);
    }
}

// -------- final: out[n,2] = concat_g(out2[g,n,:]+b2) @ Wf + bf --------------
__global__ __launch_bounds__(256) void k_final(const float* __restrict__ agg2,
                                               const float* __restrict__ b2,
                                               const float* __restrict__ Wf,
                                               const float* __restrict__ bf,
                                               float* __restrict__ out) {
    int n = blockIdx.x * 256 + threadIdx.x;
    if (n >= N_NODES) return;
    float o0 = bf[0], o1 = bf[1];
#pragma unroll
    for (int g = 0; g < G; ++g) {
        const float4* v4 = (const float4*)agg2 + (size_t)(g * N_NODES + n) * 4;
#pragma unroll
        for (int q = 0; q < 4; ++q) {
            float4 v = v4[q];
            float4 b = ((const float4*)b2)[q];
            v.x += b.x; v.y += b.y; v.z += b.z; v.w += b.w;
            int kb = g * 16 + q * 4;
            o0 += v.x * Wf[(kb + 0) * 2]     + v.y * Wf[(kb + 1) * 2]
                + v.z * Wf[(kb + 2) * 2]     + v.w * Wf[(kb + 3) * 2];
            o1 += v.x * Wf[(kb + 0) * 2 + 1] + v.y * Wf[(kb + 1) * 2 + 1]
                + v.z * Wf[(kb + 2) * 2 + 1] + v.w * Wf[(kb + 3) * 2 + 1];
        }
    }
    out[n * 2]     = o0;
    out[n * 2 + 1] = o1;
}

extern "C" void kernel_launch(void* const* d_in, const int* in_sizes, int n_in,
                              void* d_out, int out_size, void* d_ws, size_t ws_size,
                              hipStream_t stream) {
    const float* x      = (const float*)d_in[0];
    const int*   ei     = (const int*)d_in[1];
    const float* W1     = (const float*)d_in[2];
    const float* a_src1 = (const float*)d_in[3];
    const float* a_dst1 = (const float*)d_in[4];
    const float* b1     = (const float*)d_in[5];
    const float* W2     = (const float*)d_in[6];
    const float* a_src2 = (const float*)d_in[7];
    const float* a_dst2 = (const float*)d_in[8];
    const float* b2     = (const float*)d_in[9];
    const float* Wf     = (const float*)d_in[10];
    const float* bf     = (const float*)d_in[11];
    float* out = (float*)d_out;

    // workspace layout (lifetime aliasing):
    //   region A (36 MB): h1f[GN*64 u16] + l1[GN*8 u16]   (gemm1 -> layer1)
    //                     -> h2r[GN*20 u16] + out2[GN*16 f32]
    //   region B (32 MB): out1h[GN*64 u16]                (layer1 -> gemm2)
    //   region C (8 MB):  ad1[GN*8 f32] -> ad2[GN f32]
    //   ints: rowptr, deg, base_g, T, H, tmp, csr
    //   tail: W1^T hi/lo fp16 (32 KB)
    unsigned short* h1f = (unsigned short*)d_ws;             // GN*64 u16 (128B rows)
    unsigned short* l1  = h1f + (size_t)GN * 64;             // GN*8 u16
    unsigned short* h2r = h1f;                               // GN*20 u16 (alias)
    float* out2 = (float*)(h2r + (size_t)GN * 20);           // GN*16 f32 (alias; 8B-aligned)
    unsigned short* out1h = h1f + (size_t)GN * 72;           // GN*64 u16
    float* ad1  = (float*)(out1h + (size_t)GN * 64);         // GN*8 f32
    float* ad2  = ad1;                                       // GN (alias)
    int*   iws    = (int*)(ad1 + (size_t)GN * 8);
    int*   rowptr = iws;                                     // GN
    int*   deg    = rowptr + GN;                             // GN
    int*   base_g = deg + GN;                                // NBUK+1
    int*   T      = base_g + (NBUK + 1);                     // NBUK
    int*   H      = T + NBUK;                                // NBLK_E*NBUK
    int*   tmp    = H + (size_t)NBLK_E * NBUK;               // GE
    int*   csr    = tmp + GE;                                // GE
    uintptr_t wp = ((uintptr_t)(csr + GE) + 15) & ~(uintptr_t)15;
    f16* WhT = (f16*)wp;                                     // 64*128 f16
    f16* WlT = WhT + 64 * 128;                               // 64*128 f16

    // CSR build via bucket sort (no global atomics, coalesced writes)
    k_hist   <<<NBLK_E, 256, 0, stream>>>(ei, H);
    k_scanH  <<<NBUK,   256, 0, stream>>>(H, T);
    k_scanT  <<<1,      256, 0, stream>>>(T, base_g);
    k_scatter<<<NBLK_E, 256, 0, stream>>>(ei, H, base_g, tmp);
    k_build  <<<NBUK,   256, 0, stream>>>(base_g, tmp, rowptr, deg, csr);

    k_prepW  <<<32, 256, 0, stream>>>(W1, WhT, WlT);
    k_gemm1  <<<(GN + 127) / 128, 256, 0, stream>>>(x, WhT, WlT, a_src1, a_dst1, h1f, l1, ad1);
    k_layer1 <<<GN / 8, 256, 0, stream>>>(rowptr, deg, csr, h1f, l1, ad1, out1h);
    k_gemm2  <<<(GN + 63) / 64, 256, 0, stream>>>(out1h, b1, W2, a_src2, a_dst2, h2r, ad2);
    k_layer2 <<<GN / 4, 256, 0, stream>>>(rowptr, deg, csr, h2r, ad2, out2);
    k_final  <<<(N_NODES + 255) / 256, 256, 0, stream>>>(out2, b2, Wf, bf, out);
}